// Round 12
// baseline (613.981 us; speedup 1.0000x reference)
//
#include <hip/hip_runtime.h>
#include <cstdint>

#define DEV __device__ __forceinline__

typedef __attribute__((ext_vector_type(4))) float  f32x4;
typedef __attribute__((ext_vector_type(8))) short  s16x8;
typedef __attribute__((ext_vector_type(4))) unsigned short u16x4;
typedef __attribute__((ext_vector_type(8))) unsigned short u16x8;

constexpr int B_   = 2;
constexpr int S_   = 2048;
constexpr int DM   = 4096;
constexpr int HQ   = 32;
constexpr int KVH  = 8;
constexpr int DH   = 128;
constexpr int NQKV = 6144;

DEV unsigned short f2bf(float f) {
  union { float f; unsigned u; } c; c.f = f;
  unsigned u = c.u + 0x7FFFu + ((c.u >> 16) & 1u);
  return (unsigned short)(u >> 16);
}
DEV float bf2f(unsigned short h) {
  union { unsigned u; float f; } c; c.u = (unsigned)h << 16; return c.f;
}
DEV void gload16(const void* g, const void* l) {
  __builtin_amdgcn_global_load_lds(
      (const __attribute__((address_space(1))) unsigned int*)(uintptr_t)g,
      (__attribute__((address_space(3))) unsigned int*)(unsigned)(uintptr_t)l,
      16, 0, 0);
}
DEV f32x4 mfma16x16(s16x8 a, s16x8 b, f32x4 c) {
  return __builtin_amdgcn_mfma_f32_16x16x32_bf16(a, b, c, 0, 0, 0);
}

// ---------------------------------------------------------------- rope tables
__global__ __launch_bounds__(256) void k_tables(const int* __restrict__ pos,
                                                float* __restrict__ ct,
                                                float* __restrict__ st) {
  int i = blockIdx.x * 256 + threadIdx.x;
  if (i >= B_ * S_ * 64) return;
  int f = i & 63, bs = i >> 6;
  float p   = (float)pos[bs];
  float inv = __builtin_amdgcn_exp2f(-(float)f * 0.20762050593048355f);
  float a   = p * inv;
  ct[i] = cosf(a);
  st[i] = sinf(a);
}

// ------------------------------------------------------- f32 -> bf16 convert
__global__ __launch_bounds__(256) void k_cvt(const float* __restrict__ in,
                                             unsigned short* __restrict__ out,
                                             int n8) {
  int i = blockIdx.x * 256 + threadIdx.x;
  if (i >= n8) return;
  const f32x4* p = (const f32x4*)in + (size_t)2 * i;
  f32x4 a = p[0], b = p[1];
  u16x8 o;
  o[0] = f2bf(a[0]); o[1] = f2bf(a[1]); o[2] = f2bf(a[2]); o[3] = f2bf(a[3]);
  o[4] = f2bf(b[0]); o[5] = f2bf(b[1]); o[6] = f2bf(b[2]); o[7] = f2bf(b[3]);
  ((u16x8*)out)[i] = o;
}

// --------------------------------- d_out = PO0 + PO1 (bf16 partials -> f32)
__global__ __launch_bounds__(256) void k_fadd(const unsigned short* __restrict__ a,
                                              const unsigned short* __restrict__ b,
                                              float* __restrict__ o, int n8) {
  int i = blockIdx.x * 256 + threadIdx.x;
  if (i >= n8) return;
  u16x8 va = ((const u16x8*)a)[i];
  u16x8 vb = ((const u16x8*)b)[i];
  f32x4 o1, o2;
#pragma unroll
  for (int j = 0; j < 4; ++j) {
    o1[j] = bf2f(va[j]) + bf2f(vb[j]);
    o2[j] = bf2f(va[4 + j]) + bf2f(vb[4 + j]);
  }
  ((f32x4*)o)[2 * i] = o1;
  ((f32x4*)o)[2 * i + 1] = o2;
}

// -------------------------------------- f32 [R][C] -> bf16 [C][R] (transpose)
__global__ __launch_bounds__(256) void k_tconv(const float* __restrict__ in,
                                               unsigned short* __restrict__ out,
                                               int R, int C,
                                               unsigned long long ibs,
                                               unsigned long long obs) {
  __shared__ float t[64][65];
  const int r0 = blockIdx.y * 64, c0 = blockIdx.x * 64;
  const float* ib = in + (size_t)blockIdx.z * ibs;
  unsigned short* ob = out + (size_t)blockIdx.z * obs;
  const int tid = threadIdx.x, tr = tid >> 4, c4 = (tid & 15) * 4;
#pragma unroll
  for (int it = 0; it < 4; ++it) {
    int rr = it * 16 + tr;
    f32x4 v = *(const f32x4*)&ib[(size_t)(r0 + rr) * C + (c0 + c4)];
    t[rr][c4 + 0] = v[0]; t[rr][c4 + 1] = v[1];
    t[rr][c4 + 2] = v[2]; t[rr][c4 + 3] = v[3];
  }
  __syncthreads();
#pragma unroll
  for (int it = 0; it < 4; ++it) {
    int cc = it * 16 + tr;
    u16x4 o;
    o[0] = f2bf(t[c4 + 0][cc]); o[1] = f2bf(t[c4 + 1][cc]);
    o[2] = f2bf(t[c4 + 2][cc]); o[3] = f2bf(t[c4 + 3][cc]);
    *(u16x4*)&ob[(size_t)(c0 + cc) * R + (r0 + c4)] = o;
  }
}

// ---------------------------------------------------------------------------
// 256x256 8-phase bf16 GEMM (proven R3 schedule; sched_barrier(0) pin is
// load-bearing per R5 A/B).
// SPLIT=1: QKV, 2-way split-K on KV columns (bx>=16), slice1 -> Pv bf16.
// SPLIT=2: full 2-way split-K: grid 512, class c = K-slice c; class0 -> Cv
//          (bf16), class1 -> Pv (bf16); k_fadd sums into f32 output.
// ---------------------------------------------------------------------------
template <int BF16OUT, int SPLIT>
__global__ __launch_bounds__(512, 2) void k_gemm256(const unsigned short* __restrict__ A,
                                                    const unsigned short* __restrict__ BT,
                                                    void* __restrict__ Cv,
                                                    unsigned short* __restrict__ Pv,
                                                    int M, int N, int K, int NBX) {
  extern __shared__ __align__(16) char L[];  // 131072 bytes
  const int tid = threadIdx.x;
  const int lane = tid & 63, w = tid >> 6;
  const int g = lane >> 4, ml = lane & 15;
  const int wr = w & 1, wc = w >> 1;         // 2M (interleaved) x 4N

  int by, bx, koff, klen, cls = 0, ksl = 0;
  if (SPLIT == 1) {
    const int sub = (int)blockIdx.x & 255;
    const int swz = (sub & 7) * 32 + (sub >> 3);   // bijective in [0,256)
    cls = (int)blockIdx.x >> 8;
    if (cls == 0) { by = swz >> 4; bx = swz & 15; koff = 0; klen = K; }
    else {
      ksl = swz >> 7;
      int v = swz & 127;
      by = v >> 3; bx = 16 + (v & 7);
      koff = ksl * (K >> 1); klen = K >> 1;
    }
  } else if (SPLIT == 2) {
    const int sub = (int)blockIdx.x & 255;
    const int swz = (sub & 7) * 32 + (sub >> 3);
    cls = (int)blockIdx.x >> 8;
    by = swz >> 4; bx = swz & 15;
    koff = cls * (K >> 1); klen = K >> 1;
  } else {
    const int cpx = (int)gridDim.x >> 3;
    const int swz = ((int)blockIdx.x & 7) * cpx + ((int)blockIdx.x >> 3);
    by = swz / NBX; bx = swz - by * NBX; koff = 0; klen = K;
  }
  const int bm = by * 256, bn = bx * 256;

  const int srow_l = tid >> 3;
  const int scol_e = (((tid & 7) ^ ((tid >> 3) & 7)) << 3);
  const int nk = klen >> 6;

#define STAGE(kt, hf) do {                                                        \
    if ((kt) < nk) {                                                              \
      const unsigned short* sb; char* db;                                         \
      if ((hf) < 2) { sb = A  + (size_t)(bm + (hf) * 128) * K;                    \
                      db = L + ((kt) & 1) * 32768 + (hf) * 16384; }               \
      else          { sb = BT + (size_t)(bn + ((hf) - 2) * 128) * K;              \
                      db = L + 65536 + ((kt) & 1) * 32768 + ((hf) - 2) * 16384; } \
      sb += (size_t)koff + (size_t)(kt) * 64 + scol_e;                            \
      _Pragma("unroll")                                                           \
      for (int r_ = 0; r_ < 2; ++r_)                                              \
        gload16(sb + (size_t)(r_ * 64 + srow_l) * K, db + r_ * 8192 + w * 1024);  \
    } } while (0)

  f32x4 Z = {0.f, 0.f, 0.f, 0.f};
  f32x4 acc[8][4];
#pragma unroll
  for (int i = 0; i < 8; ++i)
#pragma unroll
    for (int j = 0; j < 4; ++j) acc[i][j] = Z;
  s16x8 bfr[4][2], afr[2][2];

#define FRAG(base, row, ks)                                                       \
  ((const s16x8*)((base) + ((((row) >> 7) * 16384 + ((row) & 127) * 128 +         \
                             ((ks) * 32 + 8 * g) * 2) ^ (((row) & 7) << 4))))

  // VM: 0 = none, 1 = vmcnt(6), 2 = last?0:6, 3 = last?none:6
#define PHASE(q, kbuf, SKT, SHF, VM) do {                                         \
    if ((q) == 0) {                                                               \
      _Pragma("unroll")                                                           \
      for (int nf = 0; nf < 4; ++nf)                                              \
        _Pragma("unroll")                                                         \
        for (int ks = 0; ks < 2; ++ks)                                            \
          bfr[nf][ks] = *FRAG(L + 65536 + (kbuf) * 32768,                         \
                              wc * 64 + nf * 16 + ml, ks);                        \
    }                                                                             \
    _Pragma("unroll")                                                             \
    for (int mm = 0; mm < 2; ++mm)                                                \
      _Pragma("unroll")                                                           \
      for (int ks = 0; ks < 2; ++ks)                                              \
        afr[mm][ks] = *FRAG(L + (kbuf) * 32768,                                   \
                            32 * (2 * (q) + mm) + 16 * wr + ml, ks);              \
    STAGE(SKT, SHF);                                                              \
    if ((VM) == 1) { asm volatile("s_waitcnt vmcnt(6)" ::: "memory"); }           \
    else if ((VM) == 2) {                                                         \
      if (last) { asm volatile("s_waitcnt vmcnt(0)" ::: "memory"); }              \
      else      { asm volatile("s_waitcnt vmcnt(6)" ::: "memory"); }              \
    } else if ((VM) == 3) {                                                       \
      if (!last) { asm volatile("s_waitcnt vmcnt(6)" ::: "memory"); }             \
    }                                                                             \
    __builtin_amdgcn_s_barrier();                                                 \
    asm volatile("s_waitcnt lgkmcnt(0)" ::: "memory");                            \
    __builtin_amdgcn_sched_barrier(0);                                            \
    __builtin_amdgcn_s_setprio(1);                                                \
    _Pragma("unroll")                                                             \
    for (int mm = 0; mm < 2; ++mm)                                                \
      _Pragma("unroll")                                                           \
      for (int nf = 0; nf < 4; ++nf)                                              \
        _Pragma("unroll")                                                         \
        for (int ks = 0; ks < 2; ++ks)                                            \
          acc[2 * (q) + mm][nf] =                                                 \
              mfma16x16(afr[mm][ks], bfr[nf][ks], acc[2 * (q) + mm][nf]);         \
    __builtin_amdgcn_s_setprio(0);                                                \
    __builtin_amdgcn_s_barrier();                                                 \
  } while (0)

  STAGE(0, 0); STAGE(0, 1); STAGE(0, 2); STAGE(0, 3);
  STAGE(1, 2); STAGE(1, 3); STAGE(1, 0);
  asm volatile("s_waitcnt vmcnt(6)" ::: "memory");
  __builtin_amdgcn_s_barrier();

  const int iters = nk >> 1;
  for (int i = 0; i < iters; ++i) {
    const int t = 2 * i;
    const bool last = (i == iters - 1);
    PHASE(0, 0, t + 1, 1, 0);
    PHASE(1, 0, t + 2, 2, 0);
    PHASE(2, 0, t + 2, 0, 0);
    PHASE(3, 0, t + 2, 3, 2);
    PHASE(0, 1, t + 2, 1, 0);
    PHASE(1, 1, t + 3, 2, 0);
    PHASE(2, 1, t + 3, 3, 0);
    PHASE(3, 1, t + 3, 0, 3);
  }
#undef PHASE
#undef FRAG
#undef STAGE

  const int row0 = bm + 16 * wr + 4 * g, col0 = bn + wc * 64 + ml;
  const bool toPart = (SPLIT == 1 && cls == 1 && ksl == 1) ||
                      (SPLIT == 2 && cls == 1);
#pragma unroll
  for (int m = 0; m < 8; ++m)
#pragma unroll
    for (int nf = 0; nf < 4; ++nf)
#pragma unroll
      for (int r = 0; r < 4; ++r) {
        int row = row0 + 32 * m + r;
        int col = col0 + nf * 16;
        if (BF16OUT) {
          if (toPart) {
            if (SPLIT == 1)
              Pv[(size_t)row * 2048 + (col - 4096)] = f2bf(acc[m][nf][r]);
            else
              Pv[(size_t)row * N + col] = f2bf(acc[m][nf][r]);
          } else {
            ((unsigned short*)Cv)[(size_t)row * N + col] = f2bf(acc[m][nf][r]);
          }
        } else {
          ((float*)Cv)[(size_t)row * N + col] = acc[m][nf][r];
        }
      }
}

// --------------------------- RoPE + [b,h,s,d] repack (q,k); K adds P1 partial
__global__ __launch_bounds__(256) void k_rope(const unsigned short* __restrict__ qkv,
                                              const unsigned short* __restrict__ p1,
                                              const float* __restrict__ ct,
                                              const float* __restrict__ st,
                                              unsigned short* __restrict__ qr,
                                              unsigned short* __restrict__ kr) {
  const int bs = blockIdx.x;
  const int b = bs >> 11, s = bs & 2047;
  const int tid = threadIdx.x;
  const float* cr = ct + (size_t)bs * 64;
  const float* sr = st + (size_t)bs * 64;
  const unsigned short* row = qkv + (size_t)bs * NQKV;
  {
    int h = tid >> 3, d0 = (tid & 7) * 16;
    u16x8 xs  = *(const u16x8*)&row[h * 128 + d0];
    u16x8 xs2 = *(const u16x8*)&row[h * 128 + d0 + 8];
    u16x8 xp  = *(const u16x8*)&row[h * 128 + (d0 ^ 64)];
    u16x8 xp2 = *(const u16x8*)&row[h * 128 + (d0 ^ 64) + 8];
    float sg = (d0 < 64) ? -1.f : 1.f;
    int ci = d0 & 63;
    u16x8 o1, o2;
#pragma unroll
    for (int j = 0; j < 8; ++j)
      o1[j] = f2bf(bf2f(xs[j]) * cr[ci + j] + sg * bf2f(xp[j]) * sr[ci + j]);
#pragma unroll
    for (int j = 0; j < 8; ++j)
      o2[j] = f2bf(bf2f(xs2[j]) * cr[ci + 8 + j] + sg * bf2f(xp2[j]) * sr[ci + 8 + j]);
    unsigned short* dst = qr + ((size_t)(b * HQ + h) * S_ + s) * DH + d0;
    *(u16x8*)dst = o1;
    *(u16x8*)(dst + 8) = o2;
  }
  if (tid < 64) {
    int kv = tid >> 3, d0 = (tid & 7) * 16;
    const unsigned short* krow = row + HQ * DH + kv * 128;
    const unsigned short* prow = p1 + (size_t)bs * 2048 + kv * 128;
    u16x8 xs  = *(const u16x8*)&krow[d0];
    u16x8 xs2 = *(const u16x8*)&krow[d0 + 8];
    u16x8 xp  = *(const u16x8*)&krow[d0 ^ 64];
    u16x8 xp2 = *(const u16x8*)&krow[(d0 ^ 64) + 8];
    u16x8 ys  = *(const u16x8*)&prow[d0];
    u16x8 ys2 = *(const u16x8*)&prow[d0 + 8];
    u16x8 yp  = *(const u16x8*)&prow[d0 ^ 64];
    u16x8 yp2 = *(const u16x8*)&prow[(d0 ^ 64) + 8];
    float sg = (d0 < 64) ? -1.f : 1.f;
    int ci = d0 & 63;
    u16x8 o1, o2;
#pragma unroll
    for (int j = 0; j < 8; ++j)
      o1[j] = f2bf((bf2f(xs[j]) + bf2f(ys[j])) * cr[ci + j] +
                   sg * (bf2f(xp[j]) + bf2f(yp[j])) * sr[ci + j]);
#pragma unroll
    for (int j = 0; j < 8; ++j)
      o2[j] = f2bf((bf2f(xs2[j]) + bf2f(ys2[j])) * cr[ci + 8 + j] +
                   sg * (bf2f(xp2[j]) + bf2f(yp2[j])) * sr[ci + 8 + j]);
    unsigned short* dst = kr + ((size_t)(b * KVH + kv) * S_ + s) * DH + d0;
    *(u16x8*)dst = o1;
    *(u16x8*)(dst + 8) = o2;
  }
}

// ----------------- V: [s][d] -> [d][s] per (b,kv), summing the P1 partial
__global__ __launch_bounds__(256) void k_vtrans(const unsigned short* __restrict__ qkv,
                                                const unsigned short* __restrict__ p1,
                                                unsigned short* __restrict__ vt) {
  __shared__ unsigned short t[64][65];
  const int z = blockIdx.z, b = z >> 3, kv = z & 7;
  const int s0 = blockIdx.x * 64, d0 = blockIdx.y * 64;
  const int tid = threadIdx.x, tr = tid >> 4, c4 = (tid & 15) * 4;
  const unsigned short* src = qkv + (size_t)(b * S_) * NQKV + HQ * DH + KVH * DH + kv * 128;
  const unsigned short* psr = p1 + (size_t)(b * S_) * 2048 + 1024 + kv * 128;
#pragma unroll
  for (int it = 0; it < 4; ++it) {
    int s = it * 16 + tr;
    u16x4 v = *(const u16x4*)&src[(size_t)(s0 + s) * NQKV + d0 + c4];
    u16x4 q = *(const u16x4*)&psr[(size_t)(s0 + s) * 2048 + d0 + c4];
    t[s][c4 + 0] = f2bf(bf2f(v[0]) + bf2f(q[0]));
    t[s][c4 + 1] = f2bf(bf2f(v[1]) + bf2f(q[1]));
    t[s][c4 + 2] = f2bf(bf2f(v[2]) + bf2f(q[2]));
    t[s][c4 + 3] = f2bf(bf2f(v[3]) + bf2f(q[3]));
  }
  __syncthreads();
  unsigned short* dst = vt + (size_t)(b * KVH + kv) * DH * S_;
#pragma unroll
  for (int it = 0; it < 4; ++it) {
    int d = it * 16 + tr;
    u16x4 o;
    o[0] = t[c4 + 0][d]; o[1] = t[c4 + 1][d];
    o[2] = t[c4 + 2][d]; o[3] = t[c4 + 3][d];
    *(u16x4*)&dst[(size_t)(d0 + d) * S_ + s0 + c4] = o;
  }
}

// ------------------------------------------------------- causal flash attention
// R9 paired grid + T14 async-STAGE (reg prefetch of next K/V tile, ds_write
// after barrier). DEFAULT launch bounds: R11's (256,2) hint let the allocator
// squeeze to VGPR=128 and spill (~89 MB scratch traffic/dispatch). Liveness
// ~200; let the allocator have it (2 blocks/CU, no spill).
__global__ __launch_bounds__(256) void k_attn(const unsigned short* __restrict__ qr,
                                              const unsigned short* __restrict__ kr,
                                              const unsigned short* __restrict__ vt,
                                              const unsigned short* __restrict__ wsq,
                                              const unsigned short* __restrict__ wsk,
                                              unsigned short* __restrict__ att) {
  const int h = blockIdx.y, b = blockIdx.z, kvh = h >> 2;
  const int tid = threadIdx.x, lane = tid & 63, w = tid >> 6;
  const int g = lane >> 4, ml = lane & 15;

  __shared__ unsigned short kvbuf[16384];     // 32KB: Q/K+V/Ws staging
  __shared__ unsigned short pbuf[4][32 * 68]; // 17408B, stride 68 = 34 dwords
  unsigned short* kl = kvbuf;
  unsigned short* vl = kvbuf + 8192;

  const unsigned short* Kg = kr + (size_t)(b * KVH + kvh) * S_ * DH;
  const unsigned short* Vg = vt + (size_t)(b * KVH + kvh) * DH * S_;
  const float CS = 0.12751745f;  // log2(e)/sqrt(128)
  f32x4 Z = {0.f, 0.f, 0.f, 0.f};
  u16x8 pfk[4], pfv[4];

  for (int half = 0; half < 2; ++half) {
    const int qbx = half ? (15 - (int)blockIdx.x) : (int)blockIdx.x;
    const int qb0 = qbx * 128;
    const unsigned short* Qg = qr + ((size_t)(b * HQ + h) * S_ + qb0) * DH;

    __syncthreads();  // prior half's epilogue reads of kvbuf complete
    // stage Q [128][128] swizzled (gload_lds; once per half)
#pragma unroll
    for (int it = 0; it < 8; ++it) {
      int c = w + 4 * it;
      int off = c * 1024 + lane * 16;
      int row = off >> 8;
      int sch = ((off >> 4) & 15) ^ (row & 7);
      gload16(Qg + (size_t)row * DH + sch * 8, (const char*)kvbuf + c * 1024);
    }
    // prefetch tile 0 K/V into registers (completes under the Q barrier)
#pragma unroll
    for (int i = 0; i < 4; ++i) {
      int off = i * 4096 + tid * 16;
      pfk[i] = *(const u16x8*)((const char*)Kg + (size_t)(off >> 8) * 256 + (off & 255));
      pfv[i] = *(const u16x8*)((const char*)Vg + (size_t)(off >> 7) * 4096 + (off & 127));
    }
    __syncthreads();
    s16x8 qfr[2][4];
#pragma unroll
    for (int qf = 0; qf < 2; ++qf)
#pragma unroll
      for (int ds = 0; ds < 4; ++ds) {
        int row = 32 * w + 16 * qf + ml;
        int sch = (4 * ds + g) ^ (row & 7);
        qfr[qf][ds] = *(const s16x8*)((const char*)kvbuf + row * 256 + sch * 16);
      }
    __syncthreads();  // all qfr reads done before kl/vl overwrite

    float mstate[2] = {-3e30f, -3e30f};
    float lstate[2] = {0.f, 0.f};
    f32x4 oacc[2][8];
#pragma unroll
    for (int i = 0; i < 2; ++i)
#pragma unroll
      for (int j = 0; j < 8; ++j) oacc[i][j] = Z;

    const int ntiles = (qb0 >> 6) + 2;

    for (int t = 0; t < ntiles; ++t) {
      const int kv0 = t * 64;
      // write staged tile t from registers into swizzled LDS
#pragma unroll
      for (int i = 0; i < 4; ++i) {
        int off = i * 4096 + tid * 16;
        int rk = off >> 8, ck = off & 255;
        *(u16x8*)((char*)kl + rk * 256 + (ck ^ ((rk & 7) << 4))) = pfk[i];
        int rv = off >> 7, cv = off & 127;
        *(u16x8*)((char*)vl + rv * 128 + (cv ^ ((rv & 7) << 4))) = pfv[i];
      }
      // issue tile t+1 loads (hide under this tile's compute)
      if (t + 1 < ntiles) {
        const int kv1 = kv0 + 64;
#pragma unroll
        for (int i = 0; i < 4; ++i) {
          int off = i * 4096 + tid * 16;
          pfk[i] = *(const u16x8*)((const char*)Kg + (size_t)(kv1 + (off >> 8)) * 256 + (off & 255));
          pfv[i] = *(const u16x8*)((const char*)Vg + (size_t)(off >> 7) * 4096 + kv1 * 2 + (off & 127));
        }
      }
      __syncthreads();

      f32x4 sacc[4][2];
#pragma unroll
      for (int i = 0; i < 4; ++i) { sacc[i][0] = Z; sacc[i][1] = Z; }
#pragma unroll
      for (int ds = 0; ds < 4; ++ds) {
        s16x8 af[4];
#pragma unroll
        for (int kf = 0; kf < 4; ++kf) {
          int row = 16 * kf + ml;
          int sch = (4 * ds + g) ^ (row & 7);
          af[kf] = *(const s16x8*)((const char*)kl + row * 256 + sch * 16);
        }
#pragma unroll
        for (int kf = 0; kf < 4; ++kf)
#pragma unroll
          for (int qf = 0; qf < 2; ++qf)
            sacc[kf][qf] = mfma16x16(af[kf], qfr[qf][ds], sacc[kf][qf]);
      }

      const int qg = qb0 + 32 * w + ml;
      const bool fullTile = (kv0 + 63 <= qb0 + 32 * w);
      float alpha[2];
#pragma unroll
      for (int qf = 0; qf < 2; ++qf) {
        int qq = qg + 16 * qf;
        float mx = -3e30f;
        if (fullTile) {
#pragma unroll
          for (int kf = 0; kf < 4; ++kf)
#pragma unroll
            for (int r = 0; r < 4; ++r) {
              float sv = sacc[kf][qf][r] * CS;
              sacc[kf][qf][r] = sv;
              mx = fmaxf(mx, sv);
            }
        } else {
#pragma unroll
          for (int kf = 0; kf < 4; ++kf)
#pragma unroll
            for (int r = 0; r < 4; ++r) {
              float sv = sacc[kf][qf][r] * CS;
              int kk = kv0 + 16 * kf + 4 * g + r;
              sv = (kk <= qq) ? sv : -3e30f;
              sacc[kf][qf][r] = sv;
              mx = fmaxf(mx, sv);
            }
        }
        mx = fmaxf(mx, __shfl_xor(mx, 16));
        mx = fmaxf(mx, __shfl_xor(mx, 32));
        float mn = fmaxf(mstate[qf], mx);
        alpha[qf] = __builtin_amdgcn_exp2f(mstate[qf] - mn);
        mstate[qf] = mn;
        float ls = 0.f;
#pragma unroll
        for (int kf = 0; kf < 4; ++kf) {
          u16x4 pk;
#pragma unroll
          for (int r = 0; r < 4; ++r) {
            float p = __builtin_amdgcn_exp2f(sacc[kf][qf][r] - mn);
            ls += p;
            pk[r] = f2bf(p);
          }
          *(u16x4*)&pbuf[w][(16 * qf + ml) * 68 + 16 * kf + 4 * g] = pk;
        }
        ls += __shfl_xor(ls, 16);
        ls += __shfl_xor(ls, 32);
        lstate[qf] = lstate[qf] * alpha[qf] + ls;
      }
#pragma unroll
      for (int mf = 0; mf < 2; ++mf)
#pragma unroll
        for (int r = 0; r < 4; ++r) {
          float a = __shfl(alpha[mf], (lane & 48) | (4 * g + r));
#pragma unroll
          for (int nf = 0; nf < 8; ++nf) oacc[mf][nf][r] *= a;
        }
#pragma unroll
      for (int ks = 0; ks < 2; ++ks) {
        s16x8 pa[2];
#pragma unroll
        for (int mf = 0; mf < 2; ++mf) {
          const unsigned short* pr = &pbuf[w][(16 * mf + ml) * 68 + 32 * ks + 8 * g];
          u16x4 lo = *(const u16x4*)pr;
          u16x4 hi = *(const u16x4*)(pr + 4);
          pa[mf] = (s16x8)__builtin_shufflevector(lo, hi, 0, 1, 2, 3, 4, 5, 6, 7);
        }
#pragma unroll
        for (int nf = 0; nf < 8; ++nf) {
          int row = 16 * nf + ml;
          int sch = (4 * ks + g) ^ (row & 7);
          s16x8 bv = *(const s16x8*)((const char*)vl + row * 128 + sch * 16);
#pragma unroll
          for (int mf = 0; mf < 2; ++mf)
            oacc[mf][nf] = mfma16x16(pa[mf], bv, oacc[mf][nf]);
        }
      }
      __syncthreads();   // compute reads done before next tile's ds_write
    }

    // normalize O in place
#pragma unroll
    for (int mf = 0; mf < 2; ++mf)
#pragma unroll
      for (int r = 0; r < 4; ++r) {
        float li = __shfl(lstate[mf], (lane & 48) | (4 * g + r));
        float inv = 1.0f / li;
#pragma unroll
        for (int nf = 0; nf < 8; ++nf) oacc[mf][nf][r] *= inv;
      }

    // epilogue: re-stage diagonal K rows (qb0..qb0+127) -> kfr registers
    s16x8 kfr[2][4];
#pragma unroll
    for (int it = 0; it < 8; ++it) {
      int c = w + 4 * it;
      int off = c * 1024 + lane * 16;
      int row = off >> 8;
      int sch = ((off >> 4) & 15) ^ (row & 7);
      gload16(Kg + (size_t)(qb0 + row) * DH + sch * 8, (const char*)kvbuf + c * 1024);
    }
    __syncthreads();
#pragma unroll
    for (int qf = 0; qf < 2; ++qf)
#pragma unroll
      for (int ds = 0; ds < 4; ++ds) {
        int row = 32 * w + 16 * qf + ml;
        int sch = (4 * ds + g) ^ (row & 7);
        kfr[qf][ds] = *(const s16x8*)((const char*)kvbuf + row * 256 + sch * 16);
      }

    // fused delta: O += Q*Wsq^T then += K*Wsk^T (Ws^T staged in kvbuf)
#pragma unroll
    for (int pass = 0; pass < 2; ++pass) {
      const unsigned short* Wg = (pass == 0 ? wsq : wsk) + (size_t)h * DH * DH;
      __syncthreads();
#pragma unroll
      for (int it = 0; it < 8; ++it) {
        int c = w + 4 * it;
        int off = c * 1024 + lane * 16;
        int row = off >> 8;
        int sch = ((off >> 4) & 15) ^ (row & 7);
        gload16(Wg + (size_t)row * DH + sch * 8, (const char*)kvbuf + c * 1024);
      }
      __syncthreads();
#pragma unroll
      for (int nf = 0; nf < 8; ++nf) {
        s16x8 wf[4];
#pragma unroll
        for (int ds = 0; ds < 4; ++ds) {
          int row = 16 * nf + ml;
          int sch = (4 * ds + g) ^ (row & 7);
          wf[ds] = *(const s16x8*)((const char*)kvbuf + row * 256 + sch * 16);
        }
#pragma unroll
        for (int qf = 0; qf < 2; ++qf)
#pragma unroll
          for (int ds = 0; ds < 4; ++ds)
            oacc[qf][nf] = mfma16x16(pass == 0 ? qfr[qf][ds] : kfr[qf][ds],
                                     wf[ds], oacc[qf][nf]);
      }
    }

    // write bf16 att[b][s][h*128+d]
#pragma unroll
    for (int mf = 0; mf < 2; ++mf)
#pragma unroll
      for (int r = 0; r < 4; ++r) {
        int rowg = b * S_ + qb0 + 32 * w + 16 * mf + 4 * g + r;
        size_t base = (size_t)rowg * (HQ * DH) + h * DH;
#pragma unroll
        for (int nf = 0; nf < 8; ++nf)
          att[base + 16 * nf + ml] = f2bf(oacc[mf][nf][r]);
      }
  }
}

// ---------------------------------------------------------------- launcher
extern "C" void kernel_launch(void* const* d_in, const int* in_sizes, int n_in,
                              void* d_out, int out_size, void* d_ws, size_t ws_size,
                              hipStream_t stream) {
  const float* hidden = (const float*)d_in[0];
  const int*   pos    = (const int*)d_in[1];
  const float* Wq     = (const float*)d_in[2];
  const float* Wk     = (const float*)d_in[3];
  const float* Wv     = (const float*)d_in[4];
  const float* Wo     = (const float*)d_in[5];
  const float* Wsq    = (const float*)d_in[6];
  const float* Wsk    = (const float*)d_in[7];

  char* ws = (char*)d_ws;
  unsigned short* XB    = (unsigned short*)(ws + 0);          // dead after QKV gemm
  unsigned short* WQKVT = (unsigned short*)(ws + 33554432);   // dead after QKV gemm
  unsigned short* PO0   = XB;                                 // out-proj partial 0
  unsigned short* PO1   = WQKVT;                              // out-proj partial 1
  unsigned short* WOT   = (unsigned short*)(ws + 83886080);   // 33.55 MB
  unsigned short* P1    = WOT;                                // dead before tconv(Wo)
  unsigned short* WSQT  = (unsigned short*)(ws + 117440512);
  unsigned short* WSKT  = (unsigned short*)(ws + 118489088);
  float*          CT    = (float*)(ws + 119537664);
  float*          ST    = (float*)(ws + 120586240);
  unsigned short* QKV   = (unsigned short*)(ws + 121634816);
  unsigned short* QR    = (unsigned short*)(ws + 171966464);
  unsigned short* KR    = (unsigned short*)(ws + 205520896);
  unsigned short* VT    = (unsigned short*)(ws + 213909504);
  unsigned short* ATT   = (unsigned short*)(ws + 222298112);

  k_tables<<<1024, 256, 0, stream>>>(pos, CT, ST);
  k_cvt<<<8192, 256, 0, stream>>>(hidden, XB, 2097152);
  k_tconv<<<dim3(64, 64, 1), 256, 0, stream>>>(Wq, WQKVT, 4096, 4096, 0, 0);
  k_tconv<<<dim3(16, 64, 1), 256, 0, stream>>>(Wk, WQKVT + (size_t)4096 * 4096, 4096, 1024, 0, 0);
  k_tconv<<<dim3(16, 64, 1), 256, 0, stream>>>(Wv, WQKVT + (size_t)5120 * 4096, 4096, 1024, 0, 0);
  k_tconv<<<dim3(2, 2, 32), 256, 0, stream>>>(Wsq, WSQT, 128, 128, 16384, 16384);
  k_tconv<<<dim3(2, 2, 32), 256, 0, stream>>>(Wsk, WSKT, 128, 128, 16384, 16384);
  k_gemm256<1, 1><<<dim3(512), 512, 131072, stream>>>(XB, WQKVT, QKV, P1,
                                                      4096, 6144, 4096, 0);
  k_rope<<<4096, 256, 0, stream>>>(QKV, P1, CT, ST, QR, KR);
  k_vtrans<<<dim3(32, 2, 16), 256, 0, stream>>>(QKV, P1, VT);
  k_tconv<<<dim3(64, 64, 1), 256, 0, stream>>>(Wo, WOT, 4096, 4096, 0, 0);
  k_attn<<<dim3(8, 32, 2), 256, 0, stream>>>(QR, KR, VT, WSQT, WSKT, ATT);
  // out-projection: 2-way split-K, bf16 partials into dead XB/WQKVT regions
  k_gemm256<1, 2><<<dim3(512), 512, 131072, stream>>>(ATT, WOT, PO0, PO1,
                                                      4096, 4096, 4096, 16);
  k_fadd<<<8192, 256, 0, stream>>>(PO0, PO1, (float*)d_out, 2097152);
}

// Round 13
// 535.634 us; speedup vs baseline: 1.1463x; 1.1463x over previous
//
#include <hip/hip_runtime.h>
#include <cstdint>

#define DEV __device__ __forceinline__

typedef __attribute__((ext_vector_type(4))) float  f32x4;
typedef __attribute__((ext_vector_type(8))) short  s16x8;
typedef __attribute__((ext_vector_type(4))) unsigned short u16x4;
typedef __attribute__((ext_vector_type(8))) unsigned short u16x8;

constexpr int B_   = 2;
constexpr int S_   = 2048;
constexpr int DM   = 4096;
constexpr int HQ   = 32;
constexpr int KVH  = 8;
constexpr int DH   = 128;
constexpr int NQKV = 6144;

DEV unsigned short f2bf(float f) {
  union { float f; unsigned u; } c; c.f = f;
  unsigned u = c.u + 0x7FFFu + ((c.u >> 16) & 1u);
  return (unsigned short)(u >> 16);
}
DEV float bf2f(unsigned short h) {
  union { unsigned u; float f; } c; c.u = (unsigned)h << 16; return c.f;
}
DEV void gload16(const void* g, const void* l) {
  __builtin_amdgcn_global_load_lds(
      (const __attribute__((address_space(1))) unsigned int*)(uintptr_t)g,
      (__attribute__((address_space(3))) unsigned int*)(unsigned)(uintptr_t)l,
      16, 0, 0);
}
DEV f32x4 mfma16x16(s16x8 a, s16x8 b, f32x4 c) {
  return __builtin_amdgcn_mfma_f32_16x16x32_bf16(a, b, c, 0, 0, 0);
}

// ---------------------------------------------------------------- rope tables
__global__ __launch_bounds__(256) void k_tables(const int* __restrict__ pos,
                                                float* __restrict__ ct,
                                                float* __restrict__ st) {
  int i = blockIdx.x * 256 + threadIdx.x;
  if (i >= B_ * S_ * 64) return;
  int f = i & 63, bs = i >> 6;
  float p   = (float)pos[bs];
  float inv = __builtin_amdgcn_exp2f(-(float)f * 0.20762050593048355f);
  float a   = p * inv;
  ct[i] = cosf(a);
  st[i] = sinf(a);
}

// ------------------------------------------------------- f32 -> bf16 convert
__global__ __launch_bounds__(256) void k_cvt(const float* __restrict__ in,
                                             unsigned short* __restrict__ out,
                                             int n8) {
  int i = blockIdx.x * 256 + threadIdx.x;
  if (i >= n8) return;
  const f32x4* p = (const f32x4*)in + (size_t)2 * i;
  f32x4 a = p[0], b = p[1];
  u16x8 o;
  o[0] = f2bf(a[0]); o[1] = f2bf(a[1]); o[2] = f2bf(a[2]); o[3] = f2bf(a[3]);
  o[4] = f2bf(b[0]); o[5] = f2bf(b[1]); o[6] = f2bf(b[2]); o[7] = f2bf(b[3]);
  ((u16x8*)out)[i] = o;
}

// -------------------------------------- f32 [R][C] -> bf16 [C][R] (transpose)
__global__ __launch_bounds__(256) void k_tconv(const float* __restrict__ in,
                                               unsigned short* __restrict__ out,
                                               int R, int C,
                                               unsigned long long ibs,
                                               unsigned long long obs) {
  __shared__ float t[64][65];
  const int r0 = blockIdx.y * 64, c0 = blockIdx.x * 64;
  const float* ib = in + (size_t)blockIdx.z * ibs;
  unsigned short* ob = out + (size_t)blockIdx.z * obs;
  const int tid = threadIdx.x, tr = tid >> 4, c4 = (tid & 15) * 4;
#pragma unroll
  for (int it = 0; it < 4; ++it) {
    int rr = it * 16 + tr;
    f32x4 v = *(const f32x4*)&ib[(size_t)(r0 + rr) * C + (c0 + c4)];
    t[rr][c4 + 0] = v[0]; t[rr][c4 + 1] = v[1];
    t[rr][c4 + 2] = v[2]; t[rr][c4 + 3] = v[3];
  }
  __syncthreads();
#pragma unroll
  for (int it = 0; it < 4; ++it) {
    int cc = it * 16 + tr;
    u16x4 o;
    o[0] = f2bf(t[c4 + 0][cc]); o[1] = f2bf(t[c4 + 1][cc]);
    o[2] = f2bf(t[c4 + 2][cc]); o[3] = f2bf(t[c4 + 3][cc]);
    *(u16x4*)&ob[(size_t)(c0 + cc) * R + (r0 + c4)] = o;
  }
}

// ---------------------------------------------------------------------------
// 256x256 8-phase bf16 GEMM (proven R3 schedule; sched_barrier(0) pin is
// load-bearing per R5 A/B). SPLIT=1: QKV with 2-way split-K on KV columns.
// R12 lesson: full split-K (SPLIT=2) + fadd pass = net loss; out-proj stays
// full-K grid 256.
// ---------------------------------------------------------------------------
template <int BF16OUT, int SPLIT>
__global__ __launch_bounds__(512, 2) void k_gemm256(const unsigned short* __restrict__ A,
                                                    const unsigned short* __restrict__ BT,
                                                    void* __restrict__ Cv,
                                                    unsigned short* __restrict__ Pv,
                                                    int M, int N, int K, int NBX) {
  extern __shared__ __align__(16) char L[];  // 131072 bytes
  const int tid = threadIdx.x;
  const int lane = tid & 63, w = tid >> 6;
  const int g = lane >> 4, ml = lane & 15;
  const int wr = w & 1, wc = w >> 1;         // 2M (interleaved) x 4N

  int by, bx, koff, klen, cls = 0, ksl = 0;
  if (SPLIT) {
    const int sub = (int)blockIdx.x & 255;
    const int swz = (sub & 7) * 32 + (sub >> 3);   // bijective in [0,256)
    cls = (int)blockIdx.x >> 8;
    if (cls == 0) { by = swz >> 4; bx = swz & 15; koff = 0; klen = K; }
    else {
      ksl = swz >> 7;
      int v = swz & 127;
      by = v >> 3; bx = 16 + (v & 7);
      koff = ksl * (K >> 1); klen = K >> 1;
    }
  } else {
    const int cpx = (int)gridDim.x >> 3;
    const int swz = ((int)blockIdx.x & 7) * cpx + ((int)blockIdx.x >> 3);
    by = swz / NBX; bx = swz - by * NBX; koff = 0; klen = K;
  }
  const int bm = by * 256, bn = bx * 256;

  const int srow_l = tid >> 3;
  const int scol_e = (((tid & 7) ^ ((tid >> 3) & 7)) << 3);
  const int nk = klen >> 6;

#define STAGE(kt, hf) do {                                                        \
    if ((kt) < nk) {                                                              \
      const unsigned short* sb; char* db;                                         \
      if ((hf) < 2) { sb = A  + (size_t)(bm + (hf) * 128) * K;                    \
                      db = L + ((kt) & 1) * 32768 + (hf) * 16384; }               \
      else          { sb = BT + (size_t)(bn + ((hf) - 2) * 128) * K;              \
                      db = L + 65536 + ((kt) & 1) * 32768 + ((hf) - 2) * 16384; } \
      sb += (size_t)koff + (size_t)(kt) * 64 + scol_e;                            \
      _Pragma("unroll")                                                           \
      for (int r_ = 0; r_ < 2; ++r_)                                              \
        gload16(sb + (size_t)(r_ * 64 + srow_l) * K, db + r_ * 8192 + w * 1024);  \
    } } while (0)

  f32x4 Z = {0.f, 0.f, 0.f, 0.f};
  f32x4 acc[8][4];
#pragma unroll
  for (int i = 0; i < 8; ++i)
#pragma unroll
    for (int j = 0; j < 4; ++j) acc[i][j] = Z;
  s16x8 bfr[4][2], afr[2][2];

#define FRAG(base, row, ks)                                                       \
  ((const s16x8*)((base) + ((((row) >> 7) * 16384 + ((row) & 127) * 128 +         \
                             ((ks) * 32 + 8 * g) * 2) ^ (((row) & 7) << 4))))

  // VM: 0 = none, 1 = vmcnt(6), 2 = last?0:6, 3 = last?none:6
#define PHASE(q, kbuf, SKT, SHF, VM) do {                                         \
    if ((q) == 0) {                                                               \
      _Pragma("unroll")                                                           \
      for (int nf = 0; nf < 4; ++nf)                                              \
        _Pragma("unroll")                                                         \
        for (int ks = 0; ks < 2; ++ks)                                            \
          bfr[nf][ks] = *FRAG(L + 65536 + (kbuf) * 32768,                         \
                              wc * 64 + nf * 16 + ml, ks);                        \
    }                                                                             \
    _Pragma("unroll")                                                             \
    for (int mm = 0; mm < 2; ++mm)                                                \
      _Pragma("unroll")                                                           \
      for (int ks = 0; ks < 2; ++ks)                                              \
        afr[mm][ks] = *FRAG(L + (kbuf) * 32768,                                   \
                            32 * (2 * (q) + mm) + 16 * wr + ml, ks);              \
    STAGE(SKT, SHF);                                                              \
    if ((VM) == 1) { asm volatile("s_waitcnt vmcnt(6)" ::: "memory"); }           \
    else if ((VM) == 2) {                                                         \
      if (last) { asm volatile("s_waitcnt vmcnt(0)" ::: "memory"); }              \
      else      { asm volatile("s_waitcnt vmcnt(6)" ::: "memory"); }              \
    } else if ((VM) == 3) {                                                       \
      if (!last) { asm volatile("s_waitcnt vmcnt(6)" ::: "memory"); }             \
    }                                                                             \
    __builtin_amdgcn_s_barrier();                                                 \
    asm volatile("s_waitcnt lgkmcnt(0)" ::: "memory");                            \
    __builtin_amdgcn_sched_barrier(0);                                            \
    __builtin_amdgcn_s_setprio(1);                                                \
    _Pragma("unroll")                                                             \
    for (int mm = 0; mm < 2; ++mm)                                                \
      _Pragma("unroll")                                                           \
      for (int nf = 0; nf < 4; ++nf)                                              \
        _Pragma("unroll")                                                         \
        for (int ks = 0; ks < 2; ++ks)                                            \
          acc[2 * (q) + mm][nf] =                                                 \
              mfma16x16(afr[mm][ks], bfr[nf][ks], acc[2 * (q) + mm][nf]);         \
    __builtin_amdgcn_s_setprio(0);                                                \
    __builtin_amdgcn_s_barrier();                                                 \
  } while (0)

  STAGE(0, 0); STAGE(0, 1); STAGE(0, 2); STAGE(0, 3);
  STAGE(1, 2); STAGE(1, 3); STAGE(1, 0);
  asm volatile("s_waitcnt vmcnt(6)" ::: "memory");
  __builtin_amdgcn_s_barrier();

  const int iters = nk >> 1;
  for (int i = 0; i < iters; ++i) {
    const int t = 2 * i;
    const bool last = (i == iters - 1);
    PHASE(0, 0, t + 1, 1, 0);
    PHASE(1, 0, t + 2, 2, 0);
    PHASE(2, 0, t + 2, 0, 0);
    PHASE(3, 0, t + 2, 3, 2);
    PHASE(0, 1, t + 2, 1, 0);
    PHASE(1, 1, t + 3, 2, 0);
    PHASE(2, 1, t + 3, 3, 0);
    PHASE(3, 1, t + 3, 0, 3);
  }
#undef PHASE
#undef FRAG
#undef STAGE

  const int row0 = bm + 16 * wr + 4 * g, col0 = bn + wc * 64 + ml;
  const bool toPart = (SPLIT && cls == 1 && ksl == 1);
#pragma unroll
  for (int m = 0; m < 8; ++m)
#pragma unroll
    for (int nf = 0; nf < 4; ++nf)
#pragma unroll
      for (int r = 0; r < 4; ++r) {
        int row = row0 + 32 * m + r;
        int col = col0 + nf * 16;
        if (BF16OUT) {
          if (toPart)
            Pv[(size_t)row * 2048 + (col - 4096)] = f2bf(acc[m][nf][r]);
          else
            ((unsigned short*)Cv)[(size_t)row * N + col] = f2bf(acc[m][nf][r]);
        } else {
          ((float*)Cv)[(size_t)row * N + col] = acc[m][nf][r];
        }
      }
}

// --------------------------- RoPE + [b,h,s,d] repack (q,k); K adds P1 partial
__global__ __launch_bounds__(256) void k_rope(const unsigned short* __restrict__ qkv,
                                              const unsigned short* __restrict__ p1,
                                              const float* __restrict__ ct,
                                              const float* __restrict__ st,
                                              unsigned short* __restrict__ qr,
                                              unsigned short* __restrict__ kr) {
  const int bs = blockIdx.x;
  const int b = bs >> 11, s = bs & 2047;
  const int tid = threadIdx.x;
  const float* cr = ct + (size_t)bs * 64;
  const float* sr = st + (size_t)bs * 64;
  const unsigned short* row = qkv + (size_t)bs * NQKV;
  {
    int h = tid >> 3, d0 = (tid & 7) * 16;
    u16x8 xs  = *(const u16x8*)&row[h * 128 + d0];
    u16x8 xs2 = *(const u16x8*)&row[h * 128 + d0 + 8];
    u16x8 xp  = *(const u16x8*)&row[h * 128 + (d0 ^ 64)];
    u16x8 xp2 = *(const u16x8*)&row[h * 128 + (d0 ^ 64) + 8];
    float sg = (d0 < 64) ? -1.f : 1.f;
    int ci = d0 & 63;
    u16x8 o1, o2;
#pragma unroll
    for (int j = 0; j < 8; ++j)
      o1[j] = f2bf(bf2f(xs[j]) * cr[ci + j] + sg * bf2f(xp[j]) * sr[ci + j]);
#pragma unroll
    for (int j = 0; j < 8; ++j)
      o2[j] = f2bf(bf2f(xs2[j]) * cr[ci + 8 + j] + sg * bf2f(xp2[j]) * sr[ci + 8 + j]);
    unsigned short* dst = qr + ((size_t)(b * HQ + h) * S_ + s) * DH + d0;
    *(u16x8*)dst = o1;
    *(u16x8*)(dst + 8) = o2;
  }
  if (tid < 64) {
    int kv = tid >> 3, d0 = (tid & 7) * 16;
    const unsigned short* krow = row + HQ * DH + kv * 128;
    const unsigned short* prow = p1 + (size_t)bs * 2048 + kv * 128;
    u16x8 xs  = *(const u16x8*)&krow[d0];
    u16x8 xs2 = *(const u16x8*)&krow[d0 + 8];
    u16x8 xp  = *(const u16x8*)&krow[d0 ^ 64];
    u16x8 xp2 = *(const u16x8*)&krow[(d0 ^ 64) + 8];
    u16x8 ys  = *(const u16x8*)&prow[d0];
    u16x8 ys2 = *(const u16x8*)&prow[d0 + 8];
    u16x8 yp  = *(const u16x8*)&prow[d0 ^ 64];
    u16x8 yp2 = *(const u16x8*)&prow[(d0 ^ 64) + 8];
    float sg = (d0 < 64) ? -1.f : 1.f;
    int ci = d0 & 63;
    u16x8 o1, o2;
#pragma unroll
    for (int j = 0; j < 8; ++j)
      o1[j] = f2bf((bf2f(xs[j]) + bf2f(ys[j])) * cr[ci + j] +
                   sg * (bf2f(xp[j]) + bf2f(yp[j])) * sr[ci + j]);
#pragma unroll
    for (int j = 0; j < 8; ++j)
      o2[j] = f2bf((bf2f(xs2[j]) + bf2f(ys2[j])) * cr[ci + 8 + j] +
                   sg * (bf2f(xp2[j]) + bf2f(yp2[j])) * sr[ci + 8 + j]);
    unsigned short* dst = kr + ((size_t)(b * KVH + kv) * S_ + s) * DH + d0;
    *(u16x8*)dst = o1;
    *(u16x8*)(dst + 8) = o2;
  }
}

// ----------------- V: [s][d] -> [d][s] per (b,kv), summing the P1 partial
__global__ __launch_bounds__(256) void k_vtrans(const unsigned short* __restrict__ qkv,
                                                const unsigned short* __restrict__ p1,
                                                unsigned short* __restrict__ vt) {
  __shared__ unsigned short t[64][65];
  const int z = blockIdx.z, b = z >> 3, kv = z & 7;
  const int s0 = blockIdx.x * 64, d0 = blockIdx.y * 64;
  const int tid = threadIdx.x, tr = tid >> 4, c4 = (tid & 15) * 4;
  const unsigned short* src = qkv + (size_t)(b * S_) * NQKV + HQ * DH + KVH * DH + kv * 128;
  const unsigned short* psr = p1 + (size_t)(b * S_) * 2048 + 1024 + kv * 128;
#pragma unroll
  for (int it = 0; it < 4; ++it) {
    int s = it * 16 + tr;
    u16x4 v = *(const u16x4*)&src[(size_t)(s0 + s) * NQKV + d0 + c4];
    u16x4 q = *(const u16x4*)&psr[(size_t)(s0 + s) * 2048 + d0 + c4];
    t[s][c4 + 0] = f2bf(bf2f(v[0]) + bf2f(q[0]));
    t[s][c4 + 1] = f2bf(bf2f(v[1]) + bf2f(q[1]));
    t[s][c4 + 2] = f2bf(bf2f(v[2]) + bf2f(q[2]));
    t[s][c4 + 3] = f2bf(bf2f(v[3]) + bf2f(q[3]));
  }
  __syncthreads();
  unsigned short* dst = vt + (size_t)(b * KVH + kv) * DH * S_;
#pragma unroll
  for (int it = 0; it < 4; ++it) {
    int d = it * 16 + tr;
    u16x4 o;
    o[0] = t[c4 + 0][d]; o[1] = t[c4 + 1][d];
    o[2] = t[c4 + 2][d]; o[3] = t[c4 + 3][d];
    *(u16x4*)&dst[(size_t)(d0 + d) * S_ + s0 + c4] = o;
  }
}

// ------------------------------------------------------- causal flash attention
// R9 paired grid + T14 async-STAGE (R11, proven fastest) + T13 defer-max:
// when the tile max grows <= 8 (exp2 domain) for BOTH q-fragments, keep the
// old running max (alpha=1) and skip the O-rescale pass. P bounded by 2^8;
// f32 l and bf16 P have headroom (HK THR=8, m214v23). __all makes the skip
// wave-uniform. launch_bounds(256,2): empirically fastest (VGPR->128, 3
// blocks/CU; modest spill beats 2-block no-spill per R11/R12 A/B).
__global__ __launch_bounds__(256, 2) void k_attn(const unsigned short* __restrict__ qr,
                                                 const unsigned short* __restrict__ kr,
                                                 const unsigned short* __restrict__ vt,
                                                 const unsigned short* __restrict__ wsq,
                                                 const unsigned short* __restrict__ wsk,
                                                 unsigned short* __restrict__ att) {
  const int h = blockIdx.y, b = blockIdx.z, kvh = h >> 2;
  const int tid = threadIdx.x, lane = tid & 63, w = tid >> 6;
  const int g = lane >> 4, ml = lane & 15;

  __shared__ unsigned short kvbuf[16384];     // 32KB: Q/K+V/Ws staging
  __shared__ unsigned short pbuf[4][32 * 68]; // 17408B, stride 68 = 34 dwords
  unsigned short* kl = kvbuf;
  unsigned short* vl = kvbuf + 8192;

  const unsigned short* Kg = kr + (size_t)(b * KVH + kvh) * S_ * DH;
  const unsigned short* Vg = vt + (size_t)(b * KVH + kvh) * DH * S_;
  const float CS = 0.12751745f;  // log2(e)/sqrt(128)
  f32x4 Z = {0.f, 0.f, 0.f, 0.f};
  u16x8 pfk[4], pfv[4];

  for (int half = 0; half < 2; ++half) {
    const int qbx = half ? (15 - (int)blockIdx.x) : (int)blockIdx.x;
    const int qb0 = qbx * 128;
    const unsigned short* Qg = qr + ((size_t)(b * HQ + h) * S_ + qb0) * DH;

    __syncthreads();  // prior half's epilogue reads of kvbuf complete
    // stage Q [128][128] swizzled (gload_lds; once per half)
#pragma unroll
    for (int it = 0; it < 8; ++it) {
      int c = w + 4 * it;
      int off = c * 1024 + lane * 16;
      int row = off >> 8;
      int sch = ((off >> 4) & 15) ^ (row & 7);
      gload16(Qg + (size_t)row * DH + sch * 8, (const char*)kvbuf + c * 1024);
    }
    // prefetch tile 0 K/V into registers (completes under the Q barrier)
#pragma unroll
    for (int i = 0; i < 4; ++i) {
      int off = i * 4096 + tid * 16;
      pfk[i] = *(const u16x8*)((const char*)Kg + (size_t)(off >> 8) * 256 + (off & 255));
      pfv[i] = *(const u16x8*)((const char*)Vg + (size_t)(off >> 7) * 4096 + (off & 127));
    }
    __syncthreads();
    s16x8 qfr[2][4];
#pragma unroll
    for (int qf = 0; qf < 2; ++qf)
#pragma unroll
      for (int ds = 0; ds < 4; ++ds) {
        int row = 32 * w + 16 * qf + ml;
        int sch = (4 * ds + g) ^ (row & 7);
        qfr[qf][ds] = *(const s16x8*)((const char*)kvbuf + row * 256 + sch * 16);
      }
    __syncthreads();  // all qfr reads done before kl/vl overwrite

    float mstate[2] = {-3e30f, -3e30f};
    float lstate[2] = {0.f, 0.f};
    f32x4 oacc[2][8];
#pragma unroll
    for (int i = 0; i < 2; ++i)
#pragma unroll
      for (int j = 0; j < 8; ++j) oacc[i][j] = Z;

    const int ntiles = (qb0 >> 6) + 2;

    for (int t = 0; t < ntiles; ++t) {
      const int kv0 = t * 64;
      // write staged tile t from registers into swizzled LDS
#pragma unroll
      for (int i = 0; i < 4; ++i) {
        int off = i * 4096 + tid * 16;
        int rk = off >> 8, ck = off & 255;
        *(u16x8*)((char*)kl + rk * 256 + (ck ^ ((rk & 7) << 4))) = pfk[i];
        int rv = off >> 7, cv = off & 127;
        *(u16x8*)((char*)vl + rv * 128 + (cv ^ ((rv & 7) << 4))) = pfv[i];
      }
      // issue tile t+1 loads (hide under this tile's compute)
      if (t + 1 < ntiles) {
        const int kv1 = kv0 + 64;
#pragma unroll
        for (int i = 0; i < 4; ++i) {
          int off = i * 4096 + tid * 16;
          pfk[i] = *(const u16x8*)((const char*)Kg + (size_t)(kv1 + (off >> 8)) * 256 + (off & 255));
          pfv[i] = *(const u16x8*)((const char*)Vg + (size_t)(off >> 7) * 4096 + kv1 * 2 + (off & 127));
        }
      }
      __syncthreads();

      f32x4 sacc[4][2];
#pragma unroll
      for (int i = 0; i < 4; ++i) { sacc[i][0] = Z; sacc[i][1] = Z; }
#pragma unroll
      for (int ds = 0; ds < 4; ++ds) {
        s16x8 af[4];
#pragma unroll
        for (int kf = 0; kf < 4; ++kf) {
          int row = 16 * kf + ml;
          int sch = (4 * ds + g) ^ (row & 7);
          af[kf] = *(const s16x8*)((const char*)kl + row * 256 + sch * 16);
        }
#pragma unroll
        for (int kf = 0; kf < 4; ++kf)
#pragma unroll
          for (int qf = 0; qf < 2; ++qf)
            sacc[kf][qf] = mfma16x16(af[kf], qfr[qf][ds], sacc[kf][qf]);
      }

      const int qg = qb0 + 32 * w + ml;
      const bool fullTile = (kv0 + 63 <= qb0 + 32 * w);
      float alpha[2];
      bool keep[2];
#pragma unroll
      for (int qf = 0; qf < 2; ++qf) {
        int qq = qg + 16 * qf;
        float mx = -3e30f;
        if (fullTile) {
#pragma unroll
          for (int kf = 0; kf < 4; ++kf)
#pragma unroll
            for (int r = 0; r < 4; ++r) {
              float sv = sacc[kf][qf][r] * CS;
              sacc[kf][qf][r] = sv;
              mx = fmaxf(mx, sv);
            }
        } else {
#pragma unroll
          for (int kf = 0; kf < 4; ++kf)
#pragma unroll
            for (int r = 0; r < 4; ++r) {
              float sv = sacc[kf][qf][r] * CS;
              int kk = kv0 + 16 * kf + 4 * g + r;
              sv = (kk <= qq) ? sv : -3e30f;
              sacc[kf][qf][r] = sv;
              mx = fmaxf(mx, sv);
            }
        }
        mx = fmaxf(mx, __shfl_xor(mx, 16));
        mx = fmaxf(mx, __shfl_xor(mx, 32));
        // T13 defer-max: keep old running max if growth <= 8 (exp2 domain)
        keep[qf] = __all(mx - mstate[qf] <= 8.0f);
        float mn, al;
        if (keep[qf]) { mn = mstate[qf]; al = 1.0f; }
        else {
          mn = fmaxf(mstate[qf], mx);
          al = __builtin_amdgcn_exp2f(mstate[qf] - mn);
          mstate[qf] = mn;
        }
        alpha[qf] = al;
        float ls = 0.f;
#pragma unroll
        for (int kf = 0; kf < 4; ++kf) {
          u16x4 pk;
#pragma unroll
          for (int r = 0; r < 4; ++r) {
            float p = __builtin_amdgcn_exp2f(sacc[kf][qf][r] - mn);
            ls += p;
            pk[r] = f2bf(p);
          }
          *(u16x4*)&pbuf[w][(16 * qf + ml) * 68 + 16 * kf + 4 * g] = pk;
        }
        ls += __shfl_xor(ls, 16);
        ls += __shfl_xor(ls, 32);
        lstate[qf] = lstate[qf] * alpha[qf] + ls;
      }
      if (!(keep[0] && keep[1])) {
#pragma unroll
        for (int mf = 0; mf < 2; ++mf)
#pragma unroll
          for (int r = 0; r < 4; ++r) {
            float a = __shfl(alpha[mf], (lane & 48) | (4 * g + r));
#pragma unroll
            for (int nf = 0; nf < 8; ++nf) oacc[mf][nf][r] *= a;
          }
      }
#pragma unroll
      for (int ks = 0; ks < 2; ++ks) {
        s16x8 pa[2];
#pragma unroll
        for (int mf = 0; mf < 2; ++mf) {
          const unsigned short* pr = &pbuf[w][(16 * mf + ml) * 68 + 32 * ks + 8 * g];
          u16x4 lo = *(const u16x4*)pr;
          u16x4 hi = *(const u16x4*)(pr + 4);
          pa[mf] = (s16x8)__builtin_shufflevector(lo, hi, 0, 1, 2, 3, 4, 5, 6, 7);
        }
#pragma unroll
        for (int nf = 0; nf < 8; ++nf) {
          int row = 16 * nf + ml;
          int sch = (4 * ks + g) ^ (row & 7);
          s16x8 bv = *(const s16x8*)((const char*)vl + row * 128 + sch * 16);
#pragma unroll
          for (int mf = 0; mf < 2; ++mf)
            oacc[mf][nf] = mfma16x16(pa[mf], bv, oacc[mf][nf]);
        }
      }
      __syncthreads();   // compute reads done before next tile's ds_write
    }

    // normalize O in place
#pragma unroll
    for (int mf = 0; mf < 2; ++mf)
#pragma unroll
      for (int r = 0; r < 4; ++r) {
        float li = __shfl(lstate[mf], (lane & 48) | (4 * g + r));
        float inv = 1.0f / li;
#pragma unroll
        for (int nf = 0; nf < 8; ++nf) oacc[mf][nf][r] *= inv;
      }

    // epilogue: re-stage diagonal K rows (qb0..qb0+127) -> kfr registers
    s16x8 kfr[2][4];
#pragma unroll
    for (int it = 0; it < 8; ++it) {
      int c = w + 4 * it;
      int off = c * 1024 + lane * 16;
      int row = off >> 8;
      int sch = ((off >> 4) & 15) ^ (row & 7);
      gload16(Kg + (size_t)(qb0 + row) * DH + sch * 8, (const char*)kvbuf + c * 1024);
    }
    __syncthreads();
#pragma unroll
    for (int qf = 0; qf < 2; ++qf)
#pragma unroll
      for (int ds = 0; ds < 4; ++ds) {
        int row = 32 * w + 16 * qf + ml;
        int sch = (4 * ds + g) ^ (row & 7);
        kfr[qf][ds] = *(const s16x8*)((const char*)kvbuf + row * 256 + sch * 16);
      }

    // fused delta: O += Q*Wsq^T then += K*Wsk^T (Ws^T staged in kvbuf)
#pragma unroll
    for (int pass = 0; pass < 2; ++pass) {
      const unsigned short* Wg = (pass == 0 ? wsq : wsk) + (size_t)h * DH * DH;
      __syncthreads();
#pragma unroll
      for (int it = 0; it < 8; ++it) {
        int c = w + 4 * it;
        int off = c * 1024 + lane * 16;
        int row = off >> 8;
        int sch = ((off >> 4) & 15) ^ (row & 7);
        gload16(Wg + (size_t)row * DH + sch * 8, (const char*)kvbuf + c * 1024);
      }
      __syncthreads();
#pragma unroll
      for (int nf = 0; nf < 8; ++nf) {
        s16x8 wf[4];
#pragma unroll
        for (int ds = 0; ds < 4; ++ds) {
          int row = 16 * nf + ml;
          int sch = (4 * ds + g) ^ (row & 7);
          wf[ds] = *(const s16x8*)((const char*)kvbuf + row * 256 + sch * 16);
        }
#pragma unroll
        for (int qf = 0; qf < 2; ++qf)
#pragma unroll
          for (int ds = 0; ds < 4; ++ds)
            oacc[qf][nf] = mfma16x16(pass == 0 ? qfr[qf][ds] : kfr[qf][ds],
                                     wf[ds], oacc[qf][nf]);
      }
    }

    // write bf16 att[b][s][h*128+d]
#pragma unroll
    for (int mf = 0; mf < 2; ++mf)
#pragma unroll
      for (int r = 0; r < 4; ++r) {
        int rowg = b * S_ + qb0 + 32 * w + 16 * mf + 4 * g + r;
        size_t base = (size_t)rowg * (HQ * DH) + h * DH;
#pragma unroll
        for (int nf = 0; nf < 8; ++nf)
          att[base + 16 * nf + ml] = f2bf(oacc[mf][nf][r]);
      }
  }
}

// ---------------------------------------------------------------- launcher
extern "C" void kernel_launch(void* const* d_in, const int* in_sizes, int n_in,
                              void* d_out, int out_size, void* d_ws, size_t ws_size,
                              hipStream_t stream) {
  const float* hidden = (const float*)d_in[0];
  const int*   pos    = (const int*)d_in[1];
  const float* Wq     = (const float*)d_in[2];
  const float* Wk     = (const float*)d_in[3];
  const float* Wv     = (const float*)d_in[4];
  const float* Wo     = (const float*)d_in[5];
  const float* Wsq    = (const float*)d_in[6];
  const float* Wsk    = (const float*)d_in[7];

  char* ws = (char*)d_ws;
  unsigned short* XB    = (unsigned short*)(ws + 0);
  unsigned short* WQKVT = (unsigned short*)(ws + 33554432);
  unsigned short* WOT   = (unsigned short*)(ws + 83886080);   // 33.55 MB
  unsigned short* P1    = WOT;                                // dead before tconv(Wo)
  unsigned short* WSQT  = (unsigned short*)(ws + 117440512);
  unsigned short* WSKT  = (unsigned short*)(ws + 118489088);
  float*          CT    = (float*)(ws + 119537664);
  float*          ST    = (float*)(ws + 120586240);
  unsigned short* QKV   = (unsigned short*)(ws + 121634816);
  unsigned short* QR    = (unsigned short*)(ws + 171966464);
  unsigned short* KR    = (unsigned short*)(ws + 205520896);
  unsigned short* VT    = (unsigned short*)(ws + 213909504);
  unsigned short* ATT   = (unsigned short*)(ws + 222298112);

  k_tables<<<1024, 256, 0, stream>>>(pos, CT, ST);
  k_cvt<<<8192, 256, 0, stream>>>(hidden, XB, 2097152);
  k_tconv<<<dim3(64, 64, 1), 256, 0, stream>>>(Wq, WQKVT, 4096, 4096, 0, 0);
  k_tconv<<<dim3(16, 64, 1), 256, 0, stream>>>(Wk, WQKVT + (size_t)4096 * 4096, 4096, 1024, 0, 0);
  k_tconv<<<dim3(16, 64, 1), 256, 0, stream>>>(Wv, WQKVT + (size_t)5120 * 4096, 4096, 1024, 0, 0);
  k_tconv<<<dim3(2, 2, 32), 256, 0, stream>>>(Wsq, WSQT, 128, 128, 16384, 16384);
  k_tconv<<<dim3(2, 2, 32), 256, 0, stream>>>(Wsk, WSKT, 128, 128, 16384, 16384);
  k_gemm256<1, 1><<<dim3(512), 512, 131072, stream>>>(XB, WQKVT, QKV, P1,
                                                      4096, 6144, 4096, 0);
  k_rope<<<4096, 256, 0, stream>>>(QKV, P1, CT, ST, QR, KR);
  k_vtrans<<<dim3(32, 2, 16), 256, 0, stream>>>(QKV, P1, VT);
  k_tconv<<<dim3(64, 64, 1), 256, 0, stream>>>(Wo, WOT, 4096, 4096, 0, 0);
  k_attn<<<dim3(8, 32, 2), 256, 0, stream>>>(QR, KR, VT, WSQT, WSKT, ATT);
  k_gemm256<0, 0><<<dim3(256), 512, 131072, stream>>>(ATT, WOT, d_out, nullptr,
                                                      4096, 4096, 4096, 16);
}

// Round 14
// 535.538 us; speedup vs baseline: 1.1465x; 1.0002x over previous
//
#include <hip/hip_runtime.h>
#include <cstdint>

#define DEV __device__ __forceinline__

typedef __attribute__((ext_vector_type(4))) float  f32x4;
typedef __attribute__((ext_vector_type(8))) short  s16x8;
typedef __attribute__((ext_vector_type(4))) unsigned short u16x4;
typedef __attribute__((ext_vector_type(8))) unsigned short u16x8;

constexpr int B_   = 2;
constexpr int S_   = 2048;
constexpr int DM   = 4096;
constexpr int HQ   = 32;
constexpr int KVH  = 8;
constexpr int DH   = 128;
constexpr int NQKV = 6144;

DEV unsigned short f2bf(float f) {
  union { float f; unsigned u; } c; c.f = f;
  unsigned u = c.u + 0x7FFFu + ((c.u >> 16) & 1u);
  return (unsigned short)(u >> 16);
}
DEV float bf2f(unsigned short h) {
  union { unsigned u; float f; } c; c.u = (unsigned)h << 16; return c.f;
}
DEV void gload16(const void* g, const void* l) {
  __builtin_amdgcn_global_load_lds(
      (const __attribute__((address_space(1))) unsigned int*)(uintptr_t)g,
      (__attribute__((address_space(3))) unsigned int*)(unsigned)(uintptr_t)l,
      16, 0, 0);
}
DEV f32x4 mfma16x16(s16x8 a, s16x8 b, f32x4 c) {
  return __builtin_amdgcn_mfma_f32_16x16x32_bf16(a, b, c, 0, 0, 0);
}

// ---------------------------------------------------------------- rope tables
__global__ __launch_bounds__(256) void k_tables(const int* __restrict__ pos,
                                                float* __restrict__ ct,
                                                float* __restrict__ st) {
  int i = blockIdx.x * 256 + threadIdx.x;
  if (i >= B_ * S_ * 64) return;
  int f = i & 63, bs = i >> 6;
  float p   = (float)pos[bs];
  float inv = __builtin_amdgcn_exp2f(-(float)f * 0.20762050593048355f);
  float a   = p * inv;
  ct[i] = cosf(a);
  st[i] = sinf(a);
}

// ------------------------------------------------------- f32 -> bf16 convert
__global__ __launch_bounds__(256) void k_cvt(const float* __restrict__ in,
                                             unsigned short* __restrict__ out,
                                             int n8) {
  int i = blockIdx.x * 256 + threadIdx.x;
  if (i >= n8) return;
  const f32x4* p = (const f32x4*)in + (size_t)2 * i;
  f32x4 a = p[0], b = p[1];
  u16x8 o;
  o[0] = f2bf(a[0]); o[1] = f2bf(a[1]); o[2] = f2bf(a[2]); o[3] = f2bf(a[3]);
  o[4] = f2bf(b[0]); o[5] = f2bf(b[1]); o[6] = f2bf(b[2]); o[7] = f2bf(b[3]);
  ((u16x8*)out)[i] = o;
}

// -------------------------------------- f32 [R][C] -> bf16 [C][R] (transpose)
__global__ __launch_bounds__(256) void k_tconv(const float* __restrict__ in,
                                               unsigned short* __restrict__ out,
                                               int R, int C,
                                               unsigned long long ibs,
                                               unsigned long long obs) {
  __shared__ float t[64][65];
  const int r0 = blockIdx.y * 64, c0 = blockIdx.x * 64;
  const float* ib = in + (size_t)blockIdx.z * ibs;
  unsigned short* ob = out + (size_t)blockIdx.z * obs;
  const int tid = threadIdx.x, tr = tid >> 4, c4 = (tid & 15) * 4;
#pragma unroll
  for (int it = 0; it < 4; ++it) {
    int rr = it * 16 + tr;
    f32x4 v = *(const f32x4*)&ib[(size_t)(r0 + rr) * C + (c0 + c4)];
    t[rr][c4 + 0] = v[0]; t[rr][c4 + 1] = v[1];
    t[rr][c4 + 2] = v[2]; t[rr][c4 + 3] = v[3];
  }
  __syncthreads();
#pragma unroll
  for (int it = 0; it < 4; ++it) {
    int cc = it * 16 + tr;
    u16x4 o;
    o[0] = f2bf(t[c4 + 0][cc]); o[1] = f2bf(t[c4 + 1][cc]);
    o[2] = f2bf(t[c4 + 2][cc]); o[3] = f2bf(t[c4 + 3][cc]);
    *(u16x4*)&ob[(size_t)(c0 + cc) * R + (r0 + c4)] = o;
  }
}

// ---------------------------------------------------------------------------
// 256x256 8-phase bf16 GEMM (R3 schedule; sched_barrier(0) pin load-bearing
// per R5 A/B). MFMA nest: ks OUTERMOST -> same-accumulator dependency
// distance 8 (was 1: back-to-back dependent MFMAs serialize at result
// latency ~16cyc, not 5cyc throughput). Per-acc FP order unchanged (ks0,ks1).
// SPLIT=1: QKV with 2-way split-K on KV columns.
// ---------------------------------------------------------------------------
template <int BF16OUT, int SPLIT>
__global__ __launch_bounds__(512, 2) void k_gemm256(const unsigned short* __restrict__ A,
                                                    const unsigned short* __restrict__ BT,
                                                    void* __restrict__ Cv,
                                                    unsigned short* __restrict__ Pv,
                                                    int M, int N, int K, int NBX) {
  extern __shared__ __align__(16) char L[];  // 131072 bytes
  const int tid = threadIdx.x;
  const int lane = tid & 63, w = tid >> 6;
  const int g = lane >> 4, ml = lane & 15;
  const int wr = w & 1, wc = w >> 1;         // 2M (interleaved) x 4N

  int by, bx, koff, klen, cls = 0, ksl = 0;
  if (SPLIT) {
    const int sub = (int)blockIdx.x & 255;
    const int swz = (sub & 7) * 32 + (sub >> 3);   // bijective in [0,256)
    cls = (int)blockIdx.x >> 8;
    if (cls == 0) { by = swz >> 4; bx = swz & 15; koff = 0; klen = K; }
    else {
      ksl = swz >> 7;
      int v = swz & 127;
      by = v >> 3; bx = 16 + (v & 7);
      koff = ksl * (K >> 1); klen = K >> 1;
    }
  } else {
    const int cpx = (int)gridDim.x >> 3;
    const int swz = ((int)blockIdx.x & 7) * cpx + ((int)blockIdx.x >> 3);
    by = swz / NBX; bx = swz - by * NBX; koff = 0; klen = K;
  }
  const int bm = by * 256, bn = bx * 256;

  const int srow_l = tid >> 3;
  const int scol_e = (((tid & 7) ^ ((tid >> 3) & 7)) << 3);
  const int nk = klen >> 6;

#define STAGE(kt, hf) do {                                                        \
    if ((kt) < nk) {                                                              \
      const unsigned short* sb; char* db;                                         \
      if ((hf) < 2) { sb = A  + (size_t)(bm + (hf) * 128) * K;                    \
                      db = L + ((kt) & 1) * 32768 + (hf) * 16384; }               \
      else          { sb = BT + (size_t)(bn + ((hf) - 2) * 128) * K;              \
                      db = L + 65536 + ((kt) & 1) * 32768 + ((hf) - 2) * 16384; } \
      sb += (size_t)koff + (size_t)(kt) * 64 + scol_e;                            \
      _Pragma("unroll")                                                           \
      for (int r_ = 0; r_ < 2; ++r_)                                              \
        gload16(sb + (size_t)(r_ * 64 + srow_l) * K, db + r_ * 8192 + w * 1024);  \
    } } while (0)

  f32x4 Z = {0.f, 0.f, 0.f, 0.f};
  f32x4 acc[8][4];
#pragma unroll
  for (int i = 0; i < 8; ++i)
#pragma unroll
    for (int j = 0; j < 4; ++j) acc[i][j] = Z;
  s16x8 bfr[4][2], afr[2][2];

#define FRAG(base, row, ks)                                                       \
  ((const s16x8*)((base) + ((((row) >> 7) * 16384 + ((row) & 127) * 128 +         \
                             ((ks) * 32 + 8 * g) * 2) ^ (((row) & 7) << 4))))

  // VM: 0 = none, 1 = vmcnt(6), 2 = last?0:6, 3 = last?none:6
#define PHASE(q, kbuf, SKT, SHF, VM) do {                                         \
    if ((q) == 0) {                                                               \
      _Pragma("unroll")                                                           \
      for (int nf = 0; nf < 4; ++nf)                                              \
        _Pragma("unroll")                                                         \
        for (int ks = 0; ks < 2; ++ks)                                            \
          bfr[nf][ks] = *FRAG(L + 65536 + (kbuf) * 32768,                         \
                              wc * 64 + nf * 16 + ml, ks);                        \
    }                                                                             \
    _Pragma("unroll")                                                             \
    for (int mm = 0; mm < 2; ++mm)                                                \
      _Pragma("unroll")                                                           \
      for (int ks = 0; ks < 2; ++ks)                                              \
        afr[mm][ks] = *FRAG(L + (kbuf) * 32768,                                   \
                            32 * (2 * (q) + mm) + 16 * wr + ml, ks);              \
    STAGE(SKT, SHF);                                                              \
    if ((VM) == 1) { asm volatile("s_waitcnt vmcnt(6)" ::: "memory"); }           \
    else if ((VM) == 2) {                                                         \
      if (last) { asm volatile("s_waitcnt vmcnt(0)" ::: "memory"); }              \
      else      { asm volatile("s_waitcnt vmcnt(6)" ::: "memory"); }              \
    } else if ((VM) == 3) {                                                       \
      if (!last) { asm volatile("s_waitcnt vmcnt(6)" ::: "memory"); }             \
    }                                                                             \
    __builtin_amdgcn_s_barrier();                                                 \
    asm volatile("s_waitcnt lgkmcnt(0)" ::: "memory");                            \
    __builtin_amdgcn_sched_barrier(0);                                            \
    __builtin_amdgcn_s_setprio(1);                                                \
    _Pragma("unroll")                                                             \
    for (int ks = 0; ks < 2; ++ks)                                                \
      _Pragma("unroll")                                                           \
      for (int mm = 0; mm < 2; ++mm)                                              \
        _Pragma("unroll")                                                         \
        for (int nf = 0; nf < 4; ++nf)                                            \
          acc[2 * (q) + mm][nf] =                                                 \
              mfma16x16(afr[mm][ks], bfr[nf][ks], acc[2 * (q) + mm][nf]);         \
    __builtin_amdgcn_s_setprio(0);                                                \
    __builtin_amdgcn_s_barrier();                                                 \
  } while (0)

  STAGE(0, 0); STAGE(0, 1); STAGE(0, 2); STAGE(0, 3);
  STAGE(1, 2); STAGE(1, 3); STAGE(1, 0);
  asm volatile("s_waitcnt vmcnt(6)" ::: "memory");
  __builtin_amdgcn_s_barrier();

  const int iters = nk >> 1;
  for (int i = 0; i < iters; ++i) {
    const int t = 2 * i;
    const bool last = (i == iters - 1);
    PHASE(0, 0, t + 1, 1, 0);
    PHASE(1, 0, t + 2, 2, 0);
    PHASE(2, 0, t + 2, 0, 0);
    PHASE(3, 0, t + 2, 3, 2);
    PHASE(0, 1, t + 2, 1, 0);
    PHASE(1, 1, t + 3, 2, 0);
    PHASE(2, 1, t + 3, 3, 0);
    PHASE(3, 1, t + 3, 0, 3);
  }
#undef PHASE
#undef FRAG
#undef STAGE

  const int row0 = bm + 16 * wr + 4 * g, col0 = bn + wc * 64 + ml;
  const bool toPart = (SPLIT && cls == 1 && ksl == 1);
#pragma unroll
  for (int m = 0; m < 8; ++m)
#pragma unroll
    for (int nf = 0; nf < 4; ++nf)
#pragma unroll
      for (int r = 0; r < 4; ++r) {
        int row = row0 + 32 * m + r;
        int col = col0 + nf * 16;
        if (BF16OUT) {
          if (toPart)
            Pv[(size_t)row * 2048 + (col - 4096)] = f2bf(acc[m][nf][r]);
          else
            ((unsigned short*)Cv)[(size_t)row * N + col] = f2bf(acc[m][nf][r]);
        } else {
          ((float*)Cv)[(size_t)row * N + col] = acc[m][nf][r];
        }
      }
}

// --------------------------- RoPE + [b,h,s,d] repack (q,k); K adds P1 partial
__global__ __launch_bounds__(256) void k_rope(const unsigned short* __restrict__ qkv,
                                              const unsigned short* __restrict__ p1,
                                              const float* __restrict__ ct,
                                              const float* __restrict__ st,
                                              unsigned short* __restrict__ qr,
                                              unsigned short* __restrict__ kr) {
  const int bs = blockIdx.x;
  const int b = bs >> 11, s = bs & 2047;
  const int tid = threadIdx.x;
  const float* cr = ct + (size_t)bs * 64;
  const float* sr = st + (size_t)bs * 64;
  const unsigned short* row = qkv + (size_t)bs * NQKV;
  {
    int h = tid >> 3, d0 = (tid & 7) * 16;
    u16x8 xs  = *(const u16x8*)&row[h * 128 + d0];
    u16x8 xs2 = *(const u16x8*)&row[h * 128 + d0 + 8];
    u16x8 xp  = *(const u16x8*)&row[h * 128 + (d0 ^ 64)];
    u16x8 xp2 = *(const u16x8*)&row[h * 128 + (d0 ^ 64) + 8];
    float sg = (d0 < 64) ? -1.f : 1.f;
    int ci = d0 & 63;
    u16x8 o1, o2;
#pragma unroll
    for (int j = 0; j < 8; ++j)
      o1[j] = f2bf(bf2f(xs[j]) * cr[ci + j] + sg * bf2f(xp[j]) * sr[ci + j]);
#pragma unroll
    for (int j = 0; j < 8; ++j)
      o2[j] = f2bf(bf2f(xs2[j]) * cr[ci + 8 + j] + sg * bf2f(xp2[j]) * sr[ci + 8 + j]);
    unsigned short* dst = qr + ((size_t)(b * HQ + h) * S_ + s) * DH + d0;
    *(u16x8*)dst = o1;
    *(u16x8*)(dst + 8) = o2;
  }
  if (tid < 64) {
    int kv = tid >> 3, d0 = (tid & 7) * 16;
    const unsigned short* krow = row + HQ * DH + kv * 128;
    const unsigned short* prow = p1 + (size_t)bs * 2048 + kv * 128;
    u16x8 xs  = *(const u16x8*)&krow[d0];
    u16x8 xs2 = *(const u16x8*)&krow[d0 + 8];
    u16x8 xp  = *(const u16x8*)&krow[d0 ^ 64];
    u16x8 xp2 = *(const u16x8*)&krow[(d0 ^ 64) + 8];
    u16x8 ys  = *(const u16x8*)&prow[d0];
    u16x8 ys2 = *(const u16x8*)&prow[d0 + 8];
    u16x8 yp  = *(const u16x8*)&prow[d0 ^ 64];
    u16x8 yp2 = *(const u16x8*)&prow[(d0 ^ 64) + 8];
    float sg = (d0 < 64) ? -1.f : 1.f;
    int ci = d0 & 63;
    u16x8 o1, o2;
#pragma unroll
    for (int j = 0; j < 8; ++j)
      o1[j] = f2bf((bf2f(xs[j]) + bf2f(ys[j])) * cr[ci + j] +
                   sg * (bf2f(xp[j]) + bf2f(yp[j])) * sr[ci + j]);
#pragma unroll
    for (int j = 0; j < 8; ++j)
      o2[j] = f2bf((bf2f(xs2[j]) + bf2f(ys2[j])) * cr[ci + 8 + j] +
                   sg * (bf2f(xp2[j]) + bf2f(yp2[j])) * sr[ci + 8 + j]);
    unsigned short* dst = kr + ((size_t)(b * KVH + kv) * S_ + s) * DH + d0;
    *(u16x8*)dst = o1;
    *(u16x8*)(dst + 8) = o2;
  }
}

// ----------------- V: [s][d] -> [d][s] per (b,kv), summing the P1 partial
__global__ __launch_bounds__(256) void k_vtrans(const unsigned short* __restrict__ qkv,
                                                const unsigned short* __restrict__ p1,
                                                unsigned short* __restrict__ vt) {
  __shared__ unsigned short t[64][65];
  const int z = blockIdx.z, b = z >> 3, kv = z & 7;
  const int s0 = blockIdx.x * 64, d0 = blockIdx.y * 64;
  const int tid = threadIdx.x, tr = tid >> 4, c4 = (tid & 15) * 4;
  const unsigned short* src = qkv + (size_t)(b * S_) * NQKV + HQ * DH + KVH * DH + kv * 128;
  const unsigned short* psr = p1 + (size_t)(b * S_) * 2048 + 1024 + kv * 128;
#pragma unroll
  for (int it = 0; it < 4; ++it) {
    int s = it * 16 + tr;
    u16x4 v = *(const u16x4*)&src[(size_t)(s0 + s) * NQKV + d0 + c4];
    u16x4 q = *(const u16x4*)&psr[(size_t)(s0 + s) * 2048 + d0 + c4];
    t[s][c4 + 0] = f2bf(bf2f(v[0]) + bf2f(q[0]));
    t[s][c4 + 1] = f2bf(bf2f(v[1]) + bf2f(q[1]));
    t[s][c4 + 2] = f2bf(bf2f(v[2]) + bf2f(q[2]));
    t[s][c4 + 3] = f2bf(bf2f(v[3]) + bf2f(q[3]));
  }
  __syncthreads();
  unsigned short* dst = vt + (size_t)(b * KVH + kv) * DH * S_;
#pragma unroll
  for (int it = 0; it < 4; ++it) {
    int d = it * 16 + tr;
    u16x4 o;
    o[0] = t[c4 + 0][d]; o[1] = t[c4 + 1][d];
    o[2] = t[c4 + 2][d]; o[3] = t[c4 + 3][d];
    *(u16x4*)&dst[(size_t)(d0 + d) * S_ + s0 + c4] = o;
  }
}

// ------------------------------------------------------- causal flash attention
// R13 config (best): paired grid + T14 async-STAGE + T13 defer-max +
// launch_bounds(256,2). Delta epilogue MFMA nest reordered ds-outer
// (dependency distance 16, was 1). Same per-acc FP order.
__global__ __launch_bounds__(256, 2) void k_attn(const unsigned short* __restrict__ qr,
                                                 const unsigned short* __restrict__ kr,
                                                 const unsigned short* __restrict__ vt,
                                                 const unsigned short* __restrict__ wsq,
                                                 const unsigned short* __restrict__ wsk,
                                                 unsigned short* __restrict__ att) {
  const int h = blockIdx.y, b = blockIdx.z, kvh = h >> 2;
  const int tid = threadIdx.x, lane = tid & 63, w = tid >> 6;
  const int g = lane >> 4, ml = lane & 15;

  __shared__ unsigned short kvbuf[16384];
  __shared__ unsigned short pbuf[4][32 * 68];
  unsigned short* kl = kvbuf;
  unsigned short* vl = kvbuf + 8192;

  const unsigned short* Kg = kr + (size_t)(b * KVH + kvh) * S_ * DH;
  const unsigned short* Vg = vt + (size_t)(b * KVH + kvh) * DH * S_;
  const float CS = 0.12751745f;  // log2(e)/sqrt(128)
  f32x4 Z = {0.f, 0.f, 0.f, 0.f};
  u16x8 pfk[4], pfv[4];

  for (int half = 0; half < 2; ++half) {
    const int qbx = half ? (15 - (int)blockIdx.x) : (int)blockIdx.x;
    const int qb0 = qbx * 128;
    const unsigned short* Qg = qr + ((size_t)(b * HQ + h) * S_ + qb0) * DH;

    __syncthreads();
#pragma unroll
    for (int it = 0; it < 8; ++it) {
      int c = w + 4 * it;
      int off = c * 1024 + lane * 16;
      int row = off >> 8;
      int sch = ((off >> 4) & 15) ^ (row & 7);
      gload16(Qg + (size_t)row * DH + sch * 8, (const char*)kvbuf + c * 1024);
    }
#pragma unroll
    for (int i = 0; i < 4; ++i) {
      int off = i * 4096 + tid * 16;
      pfk[i] = *(const u16x8*)((const char*)Kg + (size_t)(off >> 8) * 256 + (off & 255));
      pfv[i] = *(const u16x8*)((const char*)Vg + (size_t)(off >> 7) * 4096 + (off & 127));
    }
    __syncthreads();
    s16x8 qfr[2][4];
#pragma unroll
    for (int qf = 0; qf < 2; ++qf)
#pragma unroll
      for (int ds = 0; ds < 4; ++ds) {
        int row = 32 * w + 16 * qf + ml;
        int sch = (4 * ds + g) ^ (row & 7);
        qfr[qf][ds] = *(const s16x8*)((const char*)kvbuf + row * 256 + sch * 16);
      }
    __syncthreads();

    float mstate[2] = {-3e30f, -3e30f};
    float lstate[2] = {0.f, 0.f};
    f32x4 oacc[2][8];
#pragma unroll
    for (int i = 0; i < 2; ++i)
#pragma unroll
      for (int j = 0; j < 8; ++j) oacc[i][j] = Z;

    const int ntiles = (qb0 >> 6) + 2;

    for (int t = 0; t < ntiles; ++t) {
      const int kv0 = t * 64;
#pragma unroll
      for (int i = 0; i < 4; ++i) {
        int off = i * 4096 + tid * 16;
        int rk = off >> 8, ck = off & 255;
        *(u16x8*)((char*)kl + rk * 256 + (ck ^ ((rk & 7) << 4))) = pfk[i];
        int rv = off >> 7, cv = off & 127;
        *(u16x8*)((char*)vl + rv * 128 + (cv ^ ((rv & 7) << 4))) = pfv[i];
      }
      if (t + 1 < ntiles) {
        const int kv1 = kv0 + 64;
#pragma unroll
        for (int i = 0; i < 4; ++i) {
          int off = i * 4096 + tid * 16;
          pfk[i] = *(const u16x8*)((const char*)Kg + (size_t)(kv1 + (off >> 8)) * 256 + (off & 255));
          pfv[i] = *(const u16x8*)((const char*)Vg + (size_t)(off >> 7) * 4096 + kv1 * 2 + (off & 127));
        }
      }
      __syncthreads();

      f32x4 sacc[4][2];
#pragma unroll
      for (int i = 0; i < 4; ++i) { sacc[i][0] = Z; sacc[i][1] = Z; }
#pragma unroll
      for (int ds = 0; ds < 4; ++ds) {
        s16x8 af[4];
#pragma unroll
        for (int kf = 0; kf < 4; ++kf) {
          int row = 16 * kf + ml;
          int sch = (4 * ds + g) ^ (row & 7);
          af[kf] = *(const s16x8*)((const char*)kl + row * 256 + sch * 16);
        }
#pragma unroll
        for (int kf = 0; kf < 4; ++kf)
#pragma unroll
          for (int qf = 0; qf < 2; ++qf)
            sacc[kf][qf] = mfma16x16(af[kf], qfr[qf][ds], sacc[kf][qf]);
      }

      const int qg = qb0 + 32 * w + ml;
      const bool fullTile = (kv0 + 63 <= qb0 + 32 * w);
      float alpha[2];
      bool keep[2];
#pragma unroll
      for (int qf = 0; qf < 2; ++qf) {
        int qq = qg + 16 * qf;
        float mx = -3e30f;
        if (fullTile) {
#pragma unroll
          for (int kf = 0; kf < 4; ++kf)
#pragma unroll
            for (int r = 0; r < 4; ++r) {
              float sv = sacc[kf][qf][r] * CS;
              sacc[kf][qf][r] = sv;
              mx = fmaxf(mx, sv);
            }
        } else {
#pragma unroll
          for (int kf = 0; kf < 4; ++kf)
#pragma unroll
            for (int r = 0; r < 4; ++r) {
              float sv = sacc[kf][qf][r] * CS;
              int kk = kv0 + 16 * kf + 4 * g + r;
              sv = (kk <= qq) ? sv : -3e30f;
              sacc[kf][qf][r] = sv;
              mx = fmaxf(mx, sv);
            }
        }
        mx = fmaxf(mx, __shfl_xor(mx, 16));
        mx = fmaxf(mx, __shfl_xor(mx, 32));
        keep[qf] = __all(mx - mstate[qf] <= 8.0f);
        float mn, al;
        if (keep[qf]) { mn = mstate[qf]; al = 1.0f; }
        else {
          mn = fmaxf(mstate[qf], mx);
          al = __builtin_amdgcn_exp2f(mstate[qf] - mn);
          mstate[qf] = mn;
        }
        alpha[qf] = al;
        float ls = 0.f;
#pragma unroll
        for (int kf = 0; kf < 4; ++kf) {
          u16x4 pk;
#pragma unroll
          for (int r = 0; r < 4; ++r) {
            float p = __builtin_amdgcn_exp2f(sacc[kf][qf][r] - mn);
            ls += p;
            pk[r] = f2bf(p);
          }
          *(u16x4*)&pbuf[w][(16 * qf + ml) * 68 + 16 * kf + 4 * g] = pk;
        }
        ls += __shfl_xor(ls, 16);
        ls += __shfl_xor(ls, 32);
        lstate[qf] = lstate[qf] * alpha[qf] + ls;
      }
      if (!(keep[0] && keep[1])) {
#pragma unroll
        for (int mf = 0; mf < 2; ++mf)
#pragma unroll
          for (int r = 0; r < 4; ++r) {
            float a = __shfl(alpha[mf], (lane & 48) | (4 * g + r));
#pragma unroll
            for (int nf = 0; nf < 8; ++nf) oacc[mf][nf][r] *= a;
          }
      }
#pragma unroll
      for (int ks = 0; ks < 2; ++ks) {
        s16x8 pa[2];
#pragma unroll
        for (int mf = 0; mf < 2; ++mf) {
          const unsigned short* pr = &pbuf[w][(16 * mf + ml) * 68 + 32 * ks + 8 * g];
          u16x4 lo = *(const u16x4*)pr;
          u16x4 hi = *(const u16x4*)(pr + 4);
          pa[mf] = (s16x8)__builtin_shufflevector(lo, hi, 0, 1, 2, 3, 4, 5, 6, 7);
        }
#pragma unroll
        for (int nf = 0; nf < 8; ++nf) {
          int row = 16 * nf + ml;
          int sch = (4 * ks + g) ^ (row & 7);
          s16x8 bv = *(const s16x8*)((const char*)vl + row * 128 + sch * 16);
#pragma unroll
          for (int mf = 0; mf < 2; ++mf)
            oacc[mf][nf] = mfma16x16(pa[mf], bv, oacc[mf][nf]);
        }
      }
      __syncthreads();
    }

    // normalize O in place
#pragma unroll
    for (int mf = 0; mf < 2; ++mf)
#pragma unroll
      for (int r = 0; r < 4; ++r) {
        float li = __shfl(lstate[mf], (lane & 48) | (4 * g + r));
        float inv = 1.0f / li;
#pragma unroll
        for (int nf = 0; nf < 8; ++nf) oacc[mf][nf][r] *= inv;
      }

    // epilogue: re-stage diagonal K rows -> kfr registers
    s16x8 kfr[2][4];
#pragma unroll
    for (int it = 0; it < 8; ++it) {
      int c = w + 4 * it;
      int off = c * 1024 + lane * 16;
      int row = off >> 8;
      int sch = ((off >> 4) & 15) ^ (row & 7);
      gload16(Kg + (size_t)(qb0 + row) * DH + sch * 8, (const char*)kvbuf + c * 1024);
    }
    __syncthreads();
#pragma unroll
    for (int qf = 0; qf < 2; ++qf)
#pragma unroll
      for (int ds = 0; ds < 4; ++ds) {
        int row = 32 * w + 16 * qf + ml;
        int sch = (4 * ds + g) ^ (row & 7);
        kfr[qf][ds] = *(const s16x8*)((const char*)kvbuf + row * 256 + sch * 16);
      }

    // fused delta: O += Q*Wsq^T then += K*Wsk^T (ds OUTER: dep distance 16)
#pragma unroll
    for (int pass = 0; pass < 2; ++pass) {
      const unsigned short* Wg = (pass == 0 ? wsq : wsk) + (size_t)h * DH * DH;
      __syncthreads();
#pragma unroll
      for (int it = 0; it < 8; ++it) {
        int c = w + 4 * it;
        int off = c * 1024 + lane * 16;
        int row = off >> 8;
        int sch = ((off >> 4) & 15) ^ (row & 7);
        gload16(Wg + (size_t)row * DH + sch * 8, (const char*)kvbuf + c * 1024);
      }
      __syncthreads();
#pragma unroll
      for (int ds = 0; ds < 4; ++ds)
#pragma unroll
        for (int nf = 0; nf < 8; ++nf) {
          int row = 16 * nf + ml;
          int sch = (4 * ds + g) ^ (row & 7);
          s16x8 wf = *(const s16x8*)((const char*)kvbuf + row * 256 + sch * 16);
#pragma unroll
          for (int qf = 0; qf < 2; ++qf)
            oacc[qf][nf] = mfma16x16(pass == 0 ? qfr[qf][ds] : kfr[qf][ds],
                                     wf, oacc[qf][nf]);
        }
    }

    // write bf16 att[b][s][h*128+d]
#pragma unroll
    for (int mf = 0; mf < 2; ++mf)
#pragma unroll
      for (int r = 0; r < 4; ++r) {
        int rowg = b * S_ + qb0 + 32 * w + 16 * mf + 4 * g + r;
        size_t base = (size_t)rowg * (HQ * DH) + h * DH;
#pragma unroll
        for (int nf = 0; nf < 8; ++nf)
          att[base + 16 * nf + ml] = f2bf(oacc[mf][nf][r]);
      }
  }
}

// ---------------------------------------------------------------- launcher
extern "C" void kernel_launch(void* const* d_in, const int* in_sizes, int n_in,
                              void* d_out, int out_size, void* d_ws, size_t ws_size,
                              hipStream_t stream) {
  const float* hidden = (const float*)d_in[0];
  const int*   pos    = (const int*)d_in[1];
  const float* Wq     = (const float*)d_in[2];
  const float* Wk     = (const float*)d_in[3];
  const float* Wv     = (const float*)d_in[4];
  const float* Wo     = (const float*)d_in[5];
  const float* Wsq    = (const float*)d_in[6];
  const float* Wsk    = (const float*)d_in[7];

  char* ws = (char*)d_ws;
  unsigned short* XB    = (unsigned short*)(ws + 0);
  unsigned short* WQKVT = (unsigned short*)(ws + 33554432);
  unsigned short* WOT   = (unsigned short*)(ws + 83886080);
  unsigned short* P1    = WOT;
  unsigned short* WSQT  = (unsigned short*)(ws + 117440512);
  unsigned short* WSKT  = (unsigned short*)(ws + 118489088);
  float*          CT    = (float*)(ws + 119537664);
  float*          ST    = (float*)(ws + 120586240);
  unsigned short* QKV   = (unsigned short*)(ws + 121634816);
  unsigned short* QR    = (unsigned short*)(ws + 171966464);
  unsigned short* KR    = (unsigned short*)(ws + 205520896);
  unsigned short* VT    = (unsigned short*)(ws + 213909504);
  unsigned short* ATT   = (unsigned short*)(ws + 222298112);

  k_tables<<<1024, 256, 0, stream>>>(pos, CT, ST);
  k_cvt<<<8192, 256, 0, stream>>>(hidden, XB, 2097152);
  k_tconv<<<dim3(64, 64, 1), 256, 0, stream>>>(Wq, WQKVT, 4096, 4096, 0, 0);
  k_tconv<<<dim3(16, 64, 1), 256, 0, stream>>>(Wk, WQKVT + (size_t)4096 * 4096, 4096, 1024, 0, 0);
  k_tconv<<<dim3(16, 64, 1), 256, 0, stream>>>(Wv, WQKVT + (size_t)5120 * 4096, 4096, 1024, 0, 0);
  k_tconv<<<dim3(2, 2, 32), 256, 0, stream>>>(Wsq, WSQT, 128, 128, 16384, 16384);
  k_tconv<<<dim3(2, 2, 32), 256, 0, stream>>>(Wsk, WSKT, 128, 128, 16384, 16384);
  k_gemm256<1, 1><<<dim3(512), 512, 131072, stream>>>(XB, WQKVT, QKV, P1,
                                                      4096, 6144, 4096, 0);
  k_rope<<<4096, 256, 0, stream>>>(QKV, P1, CT, ST, QR, KR);
  k_vtrans<<<dim3(32, 2, 16), 256, 0, stream>>>(QKV, P1, VT);
  k_tconv<<<dim3(64, 64, 1), 256, 0, stream>>>(Wo, WOT, 4096, 4096, 0, 0);
  k_attn<<<dim3(8, 32, 2), 256, 0, stream>>>(QR, KR, VT, WSQT, WSKT, ATT);
  k_gemm256<0, 0><<<dim3(256), 512, 131072, stream>>>(ATT, WOT, d_out, nullptr,
                                                      4096, 4096, 4096, 16);
}